// Round 13
// baseline (884.491 us; speedup 1.0000x reference)
//
#include <hip/hip_runtime.h>
#include <hip/hip_bf16.h>
#include <math.h>

typedef unsigned short ushort_t;
typedef __attribute__((ext_vector_type(8))) short short8;
typedef __attribute__((ext_vector_type(4))) float f32x4;

static __device__ __forceinline__ ushort_t f2b(float f){
  union{float f;unsigned u;}a; a.f=f;
  unsigned r = a.u + 0x7fffu + ((a.u>>16)&1u);
  return (ushort_t)(r>>16);
}
static __device__ __forceinline__ float b2f(ushort_t u){
  union{unsigned u;float f;}a; a.u=((unsigned)u)<<16; return a.f;
}
// tanh-form GELU (R10/R11-verified within threshold)
static __device__ __forceinline__ float gelu_f(float v){
  float u = 1.595769122f*v*(1.f + 0.044715f*v*v);
  return v / (1.f + __expf(-u));
}

#define GLDS16(g,l) __builtin_amdgcn_global_load_lds((const __attribute__((address_space(1))) void*)(const void*)(g), (__attribute__((address_space(3))) void*)(void*)(l), 16, 0, 0)

// XCD-chunked (m204 bijective) + stripe-grouped block mapping.
static __device__ __forceinline__ void block_map(int GM, int& by, int& bx)
{
  const int gx = gridDim.x, gy = gridDim.y;
  const int nwg = gx*gy;
  const int orig = blockIdx.y*gx + blockIdx.x;
  const int q8 = nwg >> 3, r8 = nwg & 7;
  const int xcd = orig & 7, ii = orig >> 3;
  const int wg = (xcd < r8 ? xcd*(q8+1) : r8*(q8+1) + (xcd-r8)*q8) + ii;
  const int stripe = wg / (GM*gx);
  const int rem = wg - stripe*(GM*gx);
  const int gmEff = min(GM, gy - stripe*GM);
  bx = rem / gmEff;
  by = stripe*GM + (rem - bx*gmEff);
}

// ---------------------------------------------------------------------------
// gemm256 (R9-proven): 256x128 tile, BK=64, 8 waves, 3 buffers, vmcnt(6).
// ---------------------------------------------------------------------------
template<bool GELU, int RES>
__global__ __launch_bounds__(512)
void gemm256(const ushort_t* __restrict__ A, const ushort_t* __restrict__ Bt,
             const float* __restrict__ bias, const void* __restrict__ Res,
             float* __restrict__ Cf, ushort_t* __restrict__ Cb,
             int M, int N, int K, int lda, int ldb, int ldres, int ldcf, int ldcb,
             int nb0,
             long sA0, long sA1, long sB0, long sB1, long sR0, long sR1,
             long sCf0, long sCf1, long sCb0, long sCb1, float scale)
{
  const int z = blockIdx.z;
  const int zb0 = z % nb0, zb1 = z / nb0;
  A  += zb0*sA0 + zb1*sA1;
  Bt += zb0*sB0 + zb1*sB1;
  const float* RpF = 0; const ushort_t* RpB = 0;
  if (RES==1) RpF = (const float*)Res + zb0*sR0 + zb1*sR1;
  if (RES==2) RpB = (const ushort_t*)Res + zb0*sR0 + zb1*sR1;
  if (Cf) Cf += zb0*sCf0 + zb1*sCf1;
  if (Cb) Cb += zb0*sCb0 + zb1*sCb1;

  int by, bx; block_map(4, by, bx);
  const int bm = by*256, bn = bx*128;

  __shared__ __align__(16) char AsR[3][32768];
  __shared__ __align__(16) char BsR[3][16384];

  const int tid = threadIdx.x, lane = tid&63, w = tid>>6;
  const int wr = w>>1, wc = w&1;
  const int lr = lane&15, g16 = (lane>>4)*16;
  const int rxor = (lr&7)<<4;

  f32x4 acc[4][4] = {};

  const int colElem = ((lane&7) ^ ((lane>>3)&7)) << 3;
  const int srRow = w*8 + (lane>>3);
  const ushort_t* pAst[4];
  const ushort_t* pBst[2];
#pragma unroll
  for (int a=0;a<4;a++){
    long r = min((long)(bm + a*64 + srRow), (long)M-1);
    pAst[a] = A + r*lda + colElem;
  }
#pragma unroll
  for (int b=0;b<2;b++){
    long r = min((long)(bn + b*64 + srRow), (long)N-1);
    pBst[b] = Bt + r*ldb + colElem;
  }

  const int aOff = (wr*64 + lr)*128;
  const int bOff = (wc*64 + lr)*128;
  const int NT = K >> 6;

#define STAGE256(Ad, Bd, ktEl) do { \
    GLDS16(pAst[0] + (ktEl), (Ad) + 0*8192 + w*1024); \
    GLDS16(pAst[1] + (ktEl), (Ad) + 1*8192 + w*1024); \
    GLDS16(pAst[2] + (ktEl), (Ad) + 2*8192 + w*1024); \
    GLDS16(pAst[3] + (ktEl), (Ad) + 3*8192 + w*1024); \
    GLDS16(pBst[0] + (ktEl), (Bd) + 0*8192 + w*1024); \
    GLDS16(pBst[1] + (ktEl), (Bd) + 1*8192 + w*1024); \
  } while(0)

  char *Ac = AsR[0], *An1 = AsR[1], *An2 = AsR[2];
  char *Bc = BsR[0], *Bn1 = BsR[1], *Bn2 = BsR[2];

  STAGE256(Ac, Bc, 0);
  if (NT > 1) STAGE256(An1, Bn1, 64);
  asm volatile("s_waitcnt vmcnt(6)" ::: "memory");
  __builtin_amdgcn_s_barrier();

  for (int t=0; t<NT; ++t){
    short8 a0[4], b0[4], a1[4], b1[4];

#pragma unroll
    for (int m=0;m<4;m++) a0[m] = *(const short8*)(Ac + aOff + m*2048 + (g16 ^ rxor));
#pragma unroll
    for (int n=0;n<4;n++) b0[n] = *(const short8*)(Bc + bOff + n*2048 + (g16 ^ rxor));
    if (t+2 < NT) STAGE256(An2, Bn2, (long)(t+2)<<6);
    __builtin_amdgcn_s_barrier();
    asm volatile("s_waitcnt lgkmcnt(0)" ::: "memory");
    __builtin_amdgcn_sched_barrier(0);
    __builtin_amdgcn_s_setprio(1);
#pragma unroll
    for (int m=0;m<4;m++)
#pragma unroll
      for (int n=0;n<4;n++)
        acc[m][n] = __builtin_amdgcn_mfma_f32_16x16x32_bf16(a0[m], b0[n], acc[m][n],0,0,0);
    __builtin_amdgcn_s_setprio(0);
    __builtin_amdgcn_sched_barrier(0);
    __builtin_amdgcn_s_barrier();

#pragma unroll
    for (int m=0;m<4;m++) a1[m] = *(const short8*)(Ac + aOff + m*2048 + ((64 + g16) ^ rxor));
#pragma unroll
    for (int n=0;n<4;n++) b1[n] = *(const short8*)(Bc + bOff + n*2048 + ((64 + g16) ^ rxor));
    __builtin_amdgcn_s_barrier();
    asm volatile("s_waitcnt lgkmcnt(0)" ::: "memory");
    __builtin_amdgcn_sched_barrier(0);
    __builtin_amdgcn_s_setprio(1);
#pragma unroll
    for (int m=0;m<4;m++)
#pragma unroll
      for (int n=0;n<4;n++)
        acc[m][n] = __builtin_amdgcn_mfma_f32_16x16x32_bf16(a1[m], b1[n], acc[m][n],0,0,0);
    __builtin_amdgcn_s_setprio(0);
    __builtin_amdgcn_sched_barrier(0);
    if (t+2 < NT)      { asm volatile("s_waitcnt vmcnt(6)" ::: "memory"); }
    else if (t+1 < NT) { asm volatile("s_waitcnt vmcnt(0)" ::: "memory"); }
    __builtin_amdgcn_s_barrier();
    char* ta = Ac; Ac = An1; An1 = An2; An2 = ta;
    char* tb = Bc; Bc = Bn1; Bn1 = Bn2; Bn2 = tb;
  }
#undef STAGE256

  const int orow = bm + wr*64, ocol = bn + wc*64;
  const int rsub = (lane>>4)*4;
  float bv[4];
#pragma unroll
  for (int n=0;n<4;n++){
    const int col = ocol + n*16 + lr;
    bv[n] = (bias && col < N) ? bias[col] : 0.f;
  }
#pragma unroll
  for (int m=0;m<4;m++){
#pragma unroll
    for (int i=0;i<4;i++){
      const int row = orow + m*16 + rsub + i;
      if (row >= M) continue;
#pragma unroll
      for (int n=0;n<4;n++){
        const int col = ocol + n*16 + lr;
        if (col >= N) continue;
        float v = acc[m][n][i]*scale + bv[n];
        if (GELU) v = gelu_f(v);
        if (RES==1) v += RpF[(long)row*ldres + col];
        if (RES==2) v += b2f(RpB[(long)row*ldres + col]);
        if (Cf) Cf[(long)row*ldcf + col] = v;
        if (Cb) Cb[(long)row*ldcb + col] = f2b(v);
      }
    }
  }
}

// ---------------------------------------------------------------------------
// gemm_sb (R11/R12-proven for huge grids): 128x128 single-buffer, swizzled.
// ---------------------------------------------------------------------------
template<bool GELU, int RES>
__global__ __launch_bounds__(256)
void gemm_sb(const ushort_t* __restrict__ A, const ushort_t* __restrict__ Bt,
             const float* __restrict__ bias, const void* __restrict__ Res,
             float* __restrict__ Cf, ushort_t* __restrict__ Cb,
             int M, int N, int K, int lda, int ldb, int ldres, int ldcf, int ldcb,
             int nb0,
             long sA0, long sA1, long sB0, long sB1, long sR0, long sR1,
             long sCf0, long sCf1, long sCb0, long sCb1, float scale, int resMask)
{
  const int z = blockIdx.z;
  const int b0 = z % nb0, b1 = z / nb0;
  A  += b0*sA0 + b1*sA1;
  Bt += b0*sB0 + b1*sB1;
  const float* RpF = 0; const ushort_t* RpB = 0;
  if (RES==1) RpF = (const float*)Res + b0*sR0 + b1*sR1;
  if (RES==2) RpB = (const ushort_t*)Res + b0*sR0 + b1*sR1;
  if (Cf) Cf += b0*sCf0 + b1*sCf1;
  if (Cb) Cb += b0*sCb0 + b1*sCb1;

  int by, bx; block_map(8, by, bx);
  const int bm = by*128, bn = bx*128;

  __shared__ __align__(16) ushort_t As[4096];
  __shared__ __align__(16) ushort_t Bs[4096];
  const int tid = threadIdx.x, lane = tid&63, wave = tid>>6;
  const int wr = wave>>1, wc = wave&1;

  f32x4 acc[4][4] = {};

  const int c0 = wave*64 + lane;
  const int c1 = c0 + 256;
  const long rA0 = min(bm + (c0>>2), M-1);
  const long rA1 = min(bm + (c1>>2), M-1);
  const long rB0 = min(bn + (c0>>2), N-1);
  const long rB1 = min(bn + (c1>>2), N-1);
  const int ce0 = (((c0&3) ^ ((c0>>3)&3)) << 3);
  const int ce1 = (((c1&3) ^ ((c1>>3)&3)) << 3);
  const ushort_t* pA0 = A + rA0*lda + ce0;
  const ushort_t* pA1 = A + rA1*lda + ce1;
  const ushort_t* pB0 = Bt + rB0*ldb + ce0;
  const ushort_t* pB1 = Bt + rB1*ldb + ce1;
  const int ldsOff = wave*512;

  const int lr = lane&15, g = lane>>4;
  const int lk = ((g ^ ((lr>>1)&3)) << 3);

  for (int kt = 0; kt < K; kt += 32) {
    __syncthreads();
    GLDS16(pA0 + kt, As + ldsOff);
    GLDS16(pA1 + kt, As + 2048 + ldsOff);
    GLDS16(pB0 + kt, Bs + ldsOff);
    GLDS16(pB1 + kt, Bs + 2048 + ldsOff);
    __syncthreads();
    short8 af[4], bfv[4];
#pragma unroll
    for (int m=0;m<4;m++) af[m]  = *(const short8*)(As + (wr*64+m*16+lr)*32 + lk);
#pragma unroll
    for (int n=0;n<4;n++) bfv[n] = *(const short8*)(Bs + (wc*64+n*16+lr)*32 + lk);
#pragma unroll
    for (int m=0;m<4;m++)
#pragma unroll
      for (int n=0;n<4;n++)
        acc[m][n] = __builtin_amdgcn_mfma_f32_16x16x32_bf16(af[m], bfv[n], acc[m][n], 0, 0, 0);
  }

  const int orow = bm + wr*64, ocol = bn + wc*64;
  const int rsub = g*4;
  float bv[4];
#pragma unroll
  for (int n=0;n<4;n++){
    const int col = ocol + n*16 + lr;
    bv[n] = (bias && col < N) ? bias[col] : 0.f;
  }
#pragma unroll
  for (int m=0;m<4;m++){
#pragma unroll
    for (int i=0;i<4;i++){
      const int row = orow + m*16 + rsub + i;
      if (row >= M) continue;
#pragma unroll
      for (int n=0;n<4;n++){
        const int col = ocol + n*16 + lr;
        if (col >= N) continue;
        float v = acc[m][n][i]*scale + bv[n];
        if (GELU) v = gelu_f(v);
        if (RES==1) v += RpF[(long)(row & resMask)*ldres + col];
        if (RES==2) v += b2f(RpB[(long)(row & resMask)*ldres + col]);
        if (Cf) Cf[(long)row*ldcf + col] = v;
        if (Cb) Cb[(long)row*ldcb + col] = f2b(v);
      }
    }
  }
}

// ---------------------------------------------------------------------------
// gemm_bt (double-buffer; small/batched).
// ---------------------------------------------------------------------------
template<bool GELU, int RES>
__global__ __launch_bounds__(256)
void gemm_bt(const ushort_t* __restrict__ A, const ushort_t* __restrict__ Bt,
             const float* __restrict__ bias, const void* __restrict__ Res,
             float* __restrict__ Cf, ushort_t* __restrict__ Cb,
             int M, int N, int K, int lda, int ldb, int ldres, int ldcf, int ldcb,
             int nb0,
             long sA0, long sA1, long sB0, long sB1, long sR0, long sR1,
             long sCf0, long sCf1, long sCb0, long sCb1, float scale, int resMask)
{
  const int z = blockIdx.z;
  const int b0 = z % nb0, b1 = z / nb0;
  A  += b0*sA0 + b1*sA1;
  Bt += b0*sB0 + b1*sB1;
  const float* RpF = 0; const ushort_t* RpB = 0;
  if (RES==1) RpF = (const float*)Res + b0*sR0 + b1*sR1;
  if (RES==2) RpB = (const ushort_t*)Res + b0*sR0 + b1*sR1;
  if (Cf) Cf += b0*sCf0 + b1*sCf1;
  if (Cb) Cb += b0*sCb0 + b1*sCb1;

  int by, bx; block_map(8, by, bx);
  const int bm = by*128, bn = bx*128;

  __shared__ __align__(16) ushort_t As[2][4096];
  __shared__ __align__(16) ushort_t Bs[2][4096];
  const int tid = threadIdx.x, lane = tid&63, wave = tid>>6;
  const int wr = wave>>1, wc = wave&1;

  f32x4 acc[4][4] = {};

  const int c0 = wave*64 + lane;
  const int c1 = c0 + 256;
  const long rA0 = min(bm + (c0>>2), M-1);
  const long rA1 = min(bm + (c1>>2), M-1);
  const long rB0 = min(bn + (c0>>2), N-1);
  const long rB1 = min(bn + (c1>>2), N-1);
  const ushort_t* pA0 = A + rA0*lda + (c0&3)*8;
  const ushort_t* pA1 = A + rA1*lda + (c1&3)*8;
  const ushort_t* pB0 = Bt + rB0*ldb + (c0&3)*8;
  const ushort_t* pB1 = Bt + rB1*ldb + (c1&3)*8;
  const int ldsOff = wave*512;

  const int lr = lane&15, lk = (lane>>4)*8;

#define STAGE(buf, kt) do { \
    GLDS16(pA0 + (kt), &As[buf][ldsOff]); \
    GLDS16(pA1 + (kt), &As[buf][2048 + ldsOff]); \
    GLDS16(pB0 + (kt), &Bs[buf][ldsOff]); \
    GLDS16(pB1 + (kt), &Bs[buf][2048 + ldsOff]); \
  } while(0)

  STAGE(0, 0);
  __syncthreads();
  int cur = 0;
  for (int kt = 0; kt < K; kt += 32) {
    if (kt + 32 < K) STAGE(cur^1, kt+32);
    short8 af[4], bfv[4];
#pragma unroll
    for (int m=0;m<4;m++) af[m]  = *(const short8*)(&As[cur][(wr*64+m*16+lr)*32 + lk]);
#pragma unroll
    for (int n=0;n<4;n++) bfv[n] = *(const short8*)(&Bs[cur][(wc*64+n*16+lr)*32 + lk]);
#pragma unroll
    for (int m=0;m<4;m++)
#pragma unroll
      for (int n=0;n<4;n++)
        acc[m][n] = __builtin_amdgcn_mfma_f32_16x16x32_bf16(af[m], bfv[n], acc[m][n], 0, 0, 0);
    __syncthreads();
    cur ^= 1;
  }
#undef STAGE

  const int orow = bm + wr*64, ocol = bn + wc*64;
  const int rsub = (lane>>4)*4;
  float bv[4];
#pragma unroll
  for (int n=0;n<4;n++){
    const int col = ocol + n*16 + lr;
    bv[n] = (bias && col < N) ? bias[col] : 0.f;
  }
#pragma unroll
  for (int m=0;m<4;m++){
#pragma unroll
    for (int i=0;i<4;i++){
      const int row = orow + m*16 + rsub + i;
      if (row >= M) continue;
#pragma unroll
      for (int n=0;n<4;n++){
        const int col = ocol + n*16 + lr;
        if (col >= N) continue;
        float v = acc[m][n][i]*scale + bv[n];
        if (GELU) v = gelu_f(v);
        if (RES==1) v += RpF[(long)(row & resMask)*ldres + col];
        if (RES==2) v += b2f(RpB[(long)(row & resMask)*ldres + col]);
        if (Cf) Cf[(long)row*ldcf + col] = v;
        if (Cb) Cb[(long)row*ldcb + col] = f2b(v);
      }
    }
  }
}

// ---------------------------------------------------------------------------
// Split-K flash attention for ti (exact online softmax per chunk + combine).
// Q shared across batch (64 rows). Grid (nch,1,128). chunk = chunkTiles x 64 rows.
// Writes unnormalized o (f32) + per-row m,l partials.
// ---------------------------------------------------------------------------
__global__ __launch_bounds__(256)
void fattn_split_k(const ushort_t* __restrict__ Qb, const ushort_t* __restrict__ KVb,
                   const ushort_t* __restrict__ Vtb,
                   float* __restrict__ po, float* __restrict__ pml,
                   int LK, int ldkv, int chunkTiles, float scale)
{
  const int z = blockIdx.z, b = z >> 4, h = z & 15;
  const int c = blockIdx.x, nch = gridDim.x;
  const int tid = threadIdx.x, lane = tid & 63, wave = tid >> 6;
  const int lr = lane & 15, g = lane >> 4;

  __shared__ __align__(16) ushort_t Kls[64*68];
  __shared__ __align__(16) ushort_t Vtls[64*68];
  __shared__ __align__(16) ushort_t Pls[64*68];

  const long qrow = wave*16 + lr;   // Q shared across batch
  const short8 aq0 = *(const short8*)(Qb + qrow*1024 + h*64 + g*8);
  const short8 aq1 = *(const short8*)(Qb + qrow*1024 + h*64 + 32 + g*8);

  const ushort_t* Kbase = KVb + (long)b*LK*ldkv + h*64;
  const ushort_t* Vtbase = Vtb + (long)(b*16+h)*64*LK;

  const int r0 = tid>>3, d0c = (tid&7)*8;
  const int r1 = r0 + 32;
  const int t0 = c*chunkTiles;

  float m[4] = {-3e30f,-3e30f,-3e30f,-3e30f};
  float l[4] = {0.f,0.f,0.f,0.f};
  f32x4 o[4];
#pragma unroll
  for(int n=0;n<4;n++) o[n] = (f32x4){0.f,0.f,0.f,0.f};

  for (int tt=0; tt<chunkTiles; ++tt){
    const int t = t0 + tt;
    __syncthreads();
    { short8 v0 = *(const short8*)(Kbase + (long)(t*64 + r0)*ldkv + d0c);
      short8 v1 = *(const short8*)(Kbase + (long)(t*64 + r1)*ldkv + d0c);
      short8 w0 = *(const short8*)(Vtbase + (long)r0*LK + t*64 + d0c);
      short8 w1 = *(const short8*)(Vtbase + (long)r1*LK + t*64 + d0c);
      *(short8*)(Kls + r0*68 + d0c) = v0;
      *(short8*)(Kls + r1*68 + d0c) = v1;
      *(short8*)(Vtls + r0*68 + d0c) = w0;
      *(short8*)(Vtls + r1*68 + d0c) = w1; }
    __syncthreads();
    f32x4 s[4];
#pragma unroll
    for(int n=0;n<4;n++){
      s[n] = (f32x4){0.f,0.f,0.f,0.f};
      short8 bk0 = *(const short8*)(Kls + (n*16+lr)*68 + g*8);
      short8 bk1 = *(const short8*)(Kls + (n*16+lr)*68 + 32 + g*8);
      s[n] = __builtin_amdgcn_mfma_f32_16x16x32_bf16(aq0, bk0, s[n],0,0,0);
      s[n] = __builtin_amdgcn_mfma_f32_16x16x32_bf16(aq1, bk1, s[n],0,0,0);
    }
    float f[4];
#pragma unroll
    for(int i=0;i<4;i++){
      float mx = fmaxf(fmaxf(s[0][i],s[1][i]), fmaxf(s[2][i],s[3][i])) * scale;
#pragma unroll
      for(int o2=1;o2<16;o2<<=1) mx = fmaxf(mx, __shfl_xor(mx,o2));
      float mnew = fmaxf(m[i], mx);
      f[i] = __expf(m[i]-mnew);
      float sum = 0.f;
#pragma unroll
      for(int n=0;n<4;n++){
        float e = __expf(s[n][i]*scale - mnew);
        Pls[(wave*16 + g*4 + i)*68 + n*16 + lr] = f2b(e);
        sum += e;
      }
#pragma unroll
      for(int o2=1;o2<16;o2<<=1) sum += __shfl_xor(sum,o2);
      l[i] = l[i]*f[i] + sum;
      m[i] = mnew;
    }
    // rescale running o by f[i] (o row == m row: wave*16+g*4+i)
#pragma unroll
    for(int nd=0;nd<4;nd++)
#pragma unroll
      for(int i=0;i<4;i++) o[nd][i] *= f[i];
    short8 pa0 = *(const short8*)(Pls + (wave*16+lr)*68 + g*8);
    short8 pa1 = *(const short8*)(Pls + (wave*16+lr)*68 + 32 + g*8);
#pragma unroll
    for(int nd=0; nd<4; nd++){
      short8 vb0 = *(const short8*)(Vtls + (nd*16+lr)*68 + g*8);
      short8 vb1 = *(const short8*)(Vtls + (nd*16+lr)*68 + 32 + g*8);
      o[nd] = __builtin_amdgcn_mfma_f32_16x16x32_bf16(pa0, vb0, o[nd],0,0,0);
      o[nd] = __builtin_amdgcn_mfma_f32_16x16x32_bf16(pa1, vb1, o[nd],0,0,0);
    }
  }
  // write partials
  const long pbase = ((long)z*nch + c);
#pragma unroll
  for(int nd=0;nd<4;nd++)
#pragma unroll
    for(int i=0;i<4;i++){
      const int row = wave*16 + g*4 + i;
      po[(pbase*64 + row)*64 + nd*16 + lr] = o[nd][i];
    }
  if (lane < 16){
#pragma unroll
    for(int i=0;i<4;i++){
      const int row = wave*16 + (lane>>2)*4 + i;   // only g-consistent lanes write
    }
  }
  // m,l: each lane group (g,i) owns row wave*16+g*4+i; lane lr==0 of each group writes
  if (lr == 0){
#pragma unroll
    for(int i=0;i<4;i++){
      const int row = wave*16 + g*4 + i;
      pml[pbase*128 + row] = m[i];
      pml[pbase*128 + 64 + row] = l[i];
    }
  }
}

// combine: grid 128 blocks (one per z), 256 threads (4 waves x 64 dims)
__global__ __launch_bounds__(256)
void fcomb_k(const float* __restrict__ po, const float* __restrict__ pml,
             ushort_t* __restrict__ Ob, int nch, int oRowsPerB)
{
  const int z = blockIdx.x, b = z >> 4, h = z & 15;
  const int wave = threadIdx.x >> 6, lane = threadIdx.x & 63;
  for (int r = wave; r < 64; r += 4){
    float mstar = -3e30f;
    for (int c=0;c<nch;c++) mstar = fmaxf(mstar, pml[((long)z*nch + c)*128 + r]);
    float lstar = 0.f, oacc = 0.f;
    for (int c=0;c<nch;c++){
      const long pb = (long)z*nch + c;
      float mc = pml[pb*128 + r];
      float lc = pml[pb*128 + 64 + r];
      float fc = __expf(mc - mstar);
      lstar += lc*fc;
      oacc  += po[(pb*64 + r)*64 + lane] * fc;
    }
    Ob[((long)b*oRowsPerB + r)*1024 + h*64 + lane] = f2b(oacc / lstar);
  }
}

// ---------------------------------------------------------------------------
// Fused two-pass flash attention (tp path; unchanged, refcheck-proven).
// ---------------------------------------------------------------------------
template<bool WRITEP>
__global__ __launch_bounds__(256)
void fattn_k(const ushort_t* __restrict__ Qb, const ushort_t* __restrict__ KVb,
             const ushort_t* __restrict__ Vtb, ushort_t* __restrict__ Ob,
             ushort_t* __restrict__ Pb,
             int LK, int ldkv, int qRowsPerB, int oRowsPerB, float scale)
{
  const int z = blockIdx.z, b = z >> 4, h = z & 15;
  const int qt = blockIdx.x;
  const int tid = threadIdx.x, lane = tid & 63, wave = tid >> 6;
  const int lr = lane & 15, g = lane >> 4;

  __shared__ __align__(16) ushort_t Kls[64*68];
  __shared__ __align__(16) ushort_t Vtls[64*68];
  __shared__ __align__(16) ushort_t Pls[64*68];

  const long qrow = (long)b*qRowsPerB + qt*64 + wave*16 + lr;
  const short8 aq0 = *(const short8*)(Qb + qrow*1024 + h*64 + g*8);
  const short8 aq1 = *(const short8*)(Qb + qrow*1024 + h*64 + 32 + g*8);

  const ushort_t* Kbase = KVb + (long)b*LK*ldkv + h*64;
  const ushort_t* Vtbase = Vtb + (long)(b*16+h)*64*LK;

  const int ntiles = LK >> 6;
  const int r0 = tid>>3, d0c = (tid&7)*8;
  const int r1 = r0 + 32;

  float m[4] = {-3e30f,-3e30f,-3e30f,-3e30f};
  float l[4] = {0.f,0.f,0.f,0.f};

  for (int t=0; t<ntiles; ++t){
    __syncthreads();
    { short8 v0 = *(const short8*)(Kbase + (long)(t*64 + r0)*ldkv + d0c);
      short8 v1 = *(const short8*)(Kbase + (long)(t*64 + r1)*ldkv + d0c);
      *(short8*)(Kls + r0*68 + d0c) = v0;
      *(short8*)(Kls + r1*68 + d0c) = v1; }
    __syncthreads();
    f32x4 s[4];
#pragma unroll
    for(int n=0;n<4;n++){
      s[n] = (f32x4){0.f,0.f,0.f,0.f};
      short8 bk0 = *(const short8*)(Kls + (n*16+lr)*68 + g*8);
      short8 bk1 = *(const short8*)(Kls + (n*16+lr)*68 + 32 + g*8);
      s[n] = __builtin_amdgcn_mfma_f32_16x16x32_bf16(aq0, bk0, s[n],0,0,0);
      s[n] = __builtin_amdgcn_mfma_f32_16x16x32_bf16(aq1, bk1, s[n],0,0,0);
    }
#pragma unroll
    for(int i=0;i<4;i++){
      float mx = fmaxf(fmaxf(s[0][i],s[1][i]), fmaxf(s[2][i],s[3][i])) * scale;
#pragma unroll
      for(int o2=1;o2<16;o2<<=1) mx = fmaxf(mx, __shfl_xor(mx,o2));
      float mnew = fmaxf(m[i], mx);
      float sum = __expf(s[0][i]*scale-mnew)+__expf(s[1][i]*scale-mnew)
                + __expf(s[2][i]*scale-mnew)+__expf(s[3][i]*scale-mnew);
#pragma unroll
      for(int o2=1;o2<16;o2<<=1) sum += __shfl_xor(sum,o2);
      l[i] = l[i]*__expf(m[i]-mnew) + sum;
      m[i] = mnew;
    }
  }
  float invl[4];
#pragma unroll
  for(int i=0;i<4;i++) invl[i] = 1.f/l[i];

  f32x4 o[4];
#pragma unroll
  for(int n=0;n<4;n++) o[n] = (f32x4){0.f,0.f,0.f,0.f};

  long pbase = 0;
  if (WRITEP) pbase = ((long)(b*16+h)*1024 + qt*64 + wave*16)*320 + lr;

  for (int t=0; t<ntiles; ++t){
    __syncthreads();
    { short8 v0 = *(const short8*)(Kbase + (long)(t*64 + r0)*ldkv + d0c);
      short8 v1 = *(const short8*)(Kbase + (long)(t*64 + r1)*ldkv + d0c);
      short8 w0 = *(const short8*)(Vtbase + (long)r0*LK + t*64 + d0c);
      short8 w1 = *(const short8*)(Vtbase + (long)r1*LK + t*64 + d0c);
      *(short8*)(Kls + r0*68 + d0c) = v0;
      *(short8*)(Kls + r1*68 + d0c) = v1;
      *(short8*)(Vtls + r0*68 + d0c) = w0;
      *(short8*)(Vtls + r1*68 + d0c) = w1; }
    __syncthreads();
    f32x4 s[4];
#pragma unroll
    for(int n=0;n<4;n++){
      s[n] = (f32x4){0.f,0.f,0.f,0.f};
      short8 bk0 = *(const short8*)(Kls + (n*16+lr)*68 + g*8);
      short8 bk1 = *(const short8*)(Kls + (n*16+lr)*68 + 32 + g*8);
      s[n] = __builtin_amdgcn_mfma_f32_16x16x32_bf16(aq0, bk0, s[n],0,0,0);
      s[n] = __builtin_amdgcn_mfma_f32_16x16x32_bf16(aq1, bk1, s[n],0,0,0);
    }
#pragma unroll
    for(int n=0;n<4;n++){
#pragma unroll
      for(int i=0;i<4;i++){
        float e = __expf(s[n][i]*scale - m[i]);
        Pls[(wave*16 + g*4 + i)*68 + n*16 + lr] = f2b(e);
        if (WRITEP) Pb[pbase + (long)(g*4+i)*320 + t*64 + n*16] = f2b(e*invl[i]);
      }
    }
    short8 pa0 = *(const short8*)(Pls + (wave*16+lr)*68 + g*8);
    short8 pa1 = *(const short8*)(Pls + (wave*16+lr)*68 + 32 + g*8);
#pragma unroll
    for(int nd=0; nd<4; nd++){
      short8 vb0 = *(const short8*)(Vtls + (nd*16+lr)*68 + g*8);
      short8 vb1 = *(const short8*)(Vtls + (nd*16+lr)*68 + 32 + g*8);
      o[nd] = __builtin_amdgcn_mfma_f32_16x16x32_bf16(pa0, vb0, o[nd],0,0,0);
      o[nd] = __builtin_amdgcn_mfma_f32_16x16x32_bf16(pa1, vb1, o[nd],0,0,0);
    }
  }
  const long orow0 = (long)b*oRowsPerB + qt*64 + wave*16 + g*4;
#pragma unroll
  for(int nd=0;nd<4;nd++)
#pragma unroll
    for(int i=0;i<4;i++)
      Ob[(orow0+i)*1024 + h*64 + nd*16 + lr] = f2b(o[nd][i]*invl[i]);
}

__global__ __launch_bounds__(256)
void tcvt_k(const float* __restrict__ src, ushort_t* __restrict__ dst, int R, int C)
{
  __shared__ float t[32][33];
  int c0 = blockIdx.x*32, r0 = blockIdx.y*32;
  int tx = threadIdx.x & 31, ty = threadIdx.x >> 5;
  for (int i=ty;i<32;i+=8){ int r=r0+i, c=c0+tx; t[i][tx] = (r<R && c<C) ? src[(long)r*C + c] : 0.f; }
  __syncthreads();
  for (int i=ty;i<32;i+=8){ int c=c0+i, r=r0+tx; if (c<C && r<R) dst[(long)c*R + r] = f2b(t[tx][i]); }
}

__global__ __launch_bounds__(256)
void cvt_rows_k(const float* __restrict__ src, ushort_t* __restrict__ dst,
                long total, int R, long dstBS, long dstRO)
{
  long e = ((long)blockIdx.x*256 + threadIdx.x)*4;
  if (e >= total) return;
  long rc = e >> 10; int c = (int)(e & 1023);
  int r = (int)(rc % R); long b = rc / R;
  float4 v = *(const float4*)(src + e);
  ushort4 o; o.x=f2b(v.x); o.y=f2b(v.y); o.z=f2b(v.z); o.w=f2b(v.w);
  *(ushort4*)(dst + (b*dstBS + dstRO + r)*1024 + c) = o;
}

__global__ __launch_bounds__(256)
void vtrans_k(const ushort_t* __restrict__ V, ushort_t* __restrict__ Vt,
              int Lk, int ldv, int coloff)
{
  int b = blockIdx.z, h = blockIdx.y, k0 = blockIdx.x*32;
  __shared__ ushort_t t[32][65];
  int tx = threadIdx.x & 63, ty = threadIdx.x >> 6;
  for (int i=ty;i<32;i+=4) t[i][tx] = V[((long)b*Lk + k0 + i)*ldv + coloff + h*64 + tx];
  __syncthreads();
  int kk = threadIdx.x & 31, n0 = threadIdx.x >> 5;
  for (int n=n0;n<64;n+=8) Vt[((long)(b*16+h)*64 + n)*Lk + k0 + kk] = t[kk][n];
}

__global__ __launch_bounds__(256)
void ln2x_k(const float* __restrict__ x,
            const float* __restrict__ g1, const float* __restrict__ b1,
            const float* __restrict__ g2, const float* __restrict__ b2,
            float* __restrict__ y1f, ushort_t* __restrict__ y1b, ushort_t* __restrict__ y2b)
{
  const long row = blockIdx.x;
  int tid = threadIdx.x, lane = tid&63, wave = tid>>6;
  __shared__ float red[8], red2[8];
  float4 v = ((const float4*)(x + row*1024))[tid];
  float s = v.x+v.y+v.z+v.w;
  for (int o=32;o;o>>=1) s += __shfl_down(s,o);
  if (lane==0) red[wave]=s;
  __syncthreads();
  float mean = (red[0]+red[1]+red[2]+red[3])*(1.f/1024.f);
  float d0=v.x-mean, d1=v.y-mean, d2=v.z-mean, d3=v.w-mean;
  float q = d0*d0+d1*d1+d2*d2+d3*d3;
  for (int o=32;o;o>>=1) q += __shfl_down(q,o);
  if (lane==0) red[4+wave]=q;
  __syncthreads();
  float var = (red[4]+red[5]+red[6]+red[7])*(1.f/1024.f);
  float rs = rsqrtf(var+1e-5f);
  float4 gg=((const float4*)g1)[tid], bb=((const float4*)b1)[tid];
  float y0=d0*rs*gg.x+bb.x, y1v=d1*rs*gg.y+bb.y, y2v=d2*rs*gg.z+bb.z, y3=d3*rs*gg.w+bb.w;
  if (y1f) ((float4*)(y1f+row*1024))[tid] = make_float4(y0,y1v,y2v,y3);
  if (y1b){ ushort4 o4; o4.x=f2b(y0); o4.y=f2b(y1v); o4.z=f2b(y2v); o4.w=f2b(y3);
            ((ushort4*)(y1b+row*1024))[tid]=o4; }
  float s2 = y0+y1v+y2v+y3;
  for (int o=32;o;o>>=1) s2 += __shfl_down(s2,o);
  if (lane==0) red2[wave]=s2;
  __syncthreads();
  float mean2 = (red2[0]+red2[1]+red2[2]+red2[3])*(1.f/1024.f);
  float e0=y0-mean2,e1=y1v-mean2,e2=y2v-mean2,e3=y3-mean2;
  float q2 = e0*e0+e1*e1+e2*e2+e3*e3;
  for (int o=32;o;o>>=1) q2 += __shfl_down(q2,o);
  if (lane==0) red2[4+wave]=q2;
  __syncthreads();
  float var2 = (red2[4]+red2[5]+red2[6]+red2[7])*(1.f/1024.f);
  float rs2 = rsqrtf(var2+1e-5f);
  float4 g2v=((const float4*)g2)[tid], b2v=((const float4*)b2)[tid];
  ushort4 o4;
  o4.x=f2b(e0*rs2*g2v.x+b2v.x); o4.y=f2b(e1*rs2*g2v.y+b2v.y);
  o4.z=f2b(e2*rs2*g2v.z+b2v.z); o4.w=f2b(e3*rs2*g2v.w+b2v.w);
  ((ushort4*)(y2b+row*1024))[tid]=o4;
}

__global__ __launch_bounds__(256)
void w2ent_k(const ushort_t* __restrict__ P, float* __restrict__ rowent)
{
  int wid = (int)((blockIdx.x*256 + threadIdx.x) >> 6);
  int lane = threadIdx.x & 63;
  int b = wid >> 10, q = wid & 1023;
  const ushort_t* base = P + ((long)(b*16)*1024 + q)*320;
  float acc = 0.f;
#pragma unroll
  for (int j=0;j<5;j++){
    int k = j*64 + lane;
    float s = 0.f;
#pragma unroll
    for (int h=0;h<16;h++) s += b2f(base[(long)h*327680 + k]);
    float p = fmaxf(s*(1.f/16.f), 1e-8f);
    acc += p*__logf(p);
  }
  for (int o=32;o;o>>=1) acc += __shfl_down(acc, o);
  if (lane==0) rowent[wid] = acc;
}

__global__ __launch_bounds__(256)
void entfin_k(const float* __restrict__ rowent, float* __restrict__ out)
{
  float s = 0.f;
  for (int i=threadIdx.x;i<8192;i+=256) s += rowent[i];
  __shared__ float red[4];
  for (int o=32;o;o>>=1) s += __shfl_down(s,o);
  if ((threadIdx.x&63)==0) red[threadIdx.x>>6]=s;
  __syncthreads();
  if (threadIdx.x==0) out[0] = -(red[0]+red[1]+red[2]+red[3]) * (1.f/8192.f);
}

__global__ void dbg_k(float* out, float a){ out[0] = -12345.f; out[1] = a; }

// ---------------------------------------------------------------------------
// variant: 0 = gemm_bt (db), 1 = gemm_sb, 2 = gemm256
static void gemm(hipStream_t s, int variant, int mode,
                 const void* A, const void* Bt, const float* bias, const void* Res,
                 void* Cf, void* Cb,
                 int M, int N, int K, int lda, int ldb, int ldres, int ldcf, int ldcb,
                 int nz, int nb0,
                 long sA0, long sA1, long sB0, long sB1, long sR0, long sR1,
                 long sCf0, long sCf1, long sCb0, long sCb1, float scale, int resMask)
{
#define ARGS (const ushort_t*)A,(const ushort_t*)Bt,bias,Res,(float*)Cf,(ushort_t*)Cb,M,N,K,lda,ldb,ldres,ldcf,ldcb,nb0,sA0,sA1,sB0,sB1,sR0,sR1,sCf0,sCf1,sCb0,sCb1,scale,resMask
#define ARGS6 (const ushort_t*)A,(const ushort_t*)Bt,bias,Res,(float*)Cf,(ushort_t*)Cb,M,N,K,lda,ldb,ldres,ldcf,ldcb,nb0,sA0,sA1,sB0,sB1,sR0,sR1,sCf0,sCf1,sCb0,sCb1,scale
  if (variant == 2){
    dim3 g((N+127)/128, (M+255)/256, nz), b(512,1,1);
    if      (mode == 1) gemm256<true ,0><<<g,b,0,s>>>(ARGS6);
    else if (mode == 2) gemm256<false,1><<<g,b,0,s>>>(ARGS6);
    else if (mode == 3) gemm256<false,2><<<g,b,0,s>>>(ARGS6);
    else                gemm256<false,0><<<g,b,0,s>>>(ARGS6);
  } else if (variant == 1){
    dim3 g((N+127)/128, (M+127)/128, nz), b(256,1,1);
    if      (mode == 1) gemm_sb<true ,0><<<g,b,0,s>>>(ARGS);
    else if (mode == 2) gemm_sb<false,1><<<g,b,0,s>>>(ARGS);
    else if (mode == 3) gemm_sb<false,2><<<g,b,0,s>>>(ARGS);
    else                gemm_sb<false,0><<<g,b,0,s>>>(ARGS);
  } else {
    dim3 g((N+127)/128, (M+127)/128, nz), b(256,1,1);
    if      (mode == 1) gemm_bt<true ,0><<<g,b,0,s>>>(ARGS);
    else if (mode == 2) gemm_bt<false,1><<<g,b,0,s>>>(ARGS);
    else if (mode == 3) gemm_bt<false,2><<<g,b,0,s>>>(ARGS);
    else                gemm_bt<false,0><<<g,b,0,s>>>(ARGS);
  }
#undef ARGS
#undef ARGS6
}

extern "C" void kernel_launch(void* const* d_in, const int* in_sizes, int n_in,
                              void* d_out, int out_size, void* d_ws, size_t ws_size,
                              hipStream_t stream)
{
  const float* ptsIn = (const float*)d_in[0];
  const float* ctx   = (const float*)d_in[1];
  const float* induc = (const float*)d_in[2];
  const float* tiW[4]={(const float*)d_in[3],(const float*)d_in[4],(const float*)d_in[5],(const float*)d_in[6]};
  const float* tib[4]={(const float*)d_in[7],(const float*)d_in[8],(const float*)d_in[9],(const float*)d_in[10]};
  const float* tpW[4]={(const float*)d_in[11],(const float*)d_in[12],(const float*)d_in[13],(const float*)d_in[14]};
  const float* tpb[4]={(const float*)d_in[15],(const float*)d_in[16],(const float*)d_in[17],(const float*)d_in[18]};
  const float* iff_g=(const float*)d_in[19]; const float* iff_b=(const float*)d_in[20];
  const float* iffW1=(const float*)d_in[21]; const float* iff_b1=(const float*)d_in[22];
  const float* iffW2=(const float*)d_in[23]; const float* iff_b2=(const float*)d_in[24];
  const float* pff_g=(const float*)d_in[25]; const float* pff_b=(const float*)d_in[26];
  const float* pffW1=(const float*)d_in[27]; const float* pff_b1=(const float*)d_in[28];
  const float* pffW2=(const float*)d_in[29]; const float* pff_b2=(const float*)d_in[30];
  const float* ni_g=(const float*)d_in[31]; const float* ni_b=(const float*)d_in[32];
  const float* np_g=(const float*)d_in[33]; const float* np_b=(const float*)d_in[34];
  float* outF = (float*)d_out;

  char* ws = (char*)d_ws;
  size_t off = 0;
  auto alloc = [&](size_t bytes){ off=(off+255)&~(size_t)255; size_t o=off; off+=bytes; return o; };
  auto sub = [&](size_t& pp, size_t bytes){ pp=(pp+255)&~(size_t)255; size_t o=pp; pp+=bytes; return o; };

  // ---- persistent ----
  size_t o_tiQw  = alloc(1024L*1024*2);
  size_t o_tiKVw = alloc(2048L*1024*2);
  size_t o_tiOw  = alloc(1024L*1024*2);
  size_t o_tpQw  = alloc(1024L*1024*2);
  size_t o_tpKVw = alloc(2048L*1024*2);
  size_t o_tpOw  = alloc(1024L*1024*2);
  size_t o_iffW1t = alloc(4096L*1024*2);
  size_t o_iffW2t = alloc(4096L*1024*2);
  size_t o_pffW1t = alloc(4096L*1024*2);
  size_t o_pffW2t = alloc(4096L*1024*2);
  size_t o_bti  = alloc(2048*4);
  size_t o_btp  = alloc(2048*4);
  size_t o_indb = alloc(64L*1024*2);
  size_t o_kv   = alloc(10240L*1024*2);
  size_t o_kv2  = alloc(2560L*1024*2);
  size_t o_rowent = alloc(8192*4);
  off=(off+255)&~(size_t)255;
  size_t arena = off;

  // ---- ti phase ----
  size_t p = arena;
  size_t o_Qti     = sub(p, 64L*1024*2);
  size_t o_KVti    = sub(p, 10240L*2048*2);
  size_t o_Vtti    = sub(p, 8192L*1280*2);
  size_t o_attnOti = sub(p, 512L*1024*2);
  size_t o_po      = sub(p, 128L*10*64*64*4);
  size_t o_pml     = sub(p, 128L*10*128*4);
  size_t o_t1      = sub(p, 512L*1024*4);
  size_t o_ind1    = sub(p, 512L*1024*4);
  size_t o_h0i     = sub(p, 512L*1024*2);
  size_t o_h1i     = sub(p, 512L*4096*2);
  size_t need1 = p;
  // ---- tp phase ----
  p = arena;
  size_t o_attnOtp = sub(p, 8192L*1024*2);
  size_t shared = p;
  size_t o_Qtp  = sub(p, 8192L*1024*2);
  size_t o_KVtp = sub(p, 2560L*2048*2);
  size_t o_Vttp = sub(p, 8192L*320*2);
  size_t o_P    = sub(p, 8L*16*1024*320*2);
  size_t need3 = p;
  p = shared;
  size_t o_t2   = sub(p, 8192L*1024*4);
  size_t o_pts1 = sub(p, 8192L*1024*2);
  size_t o_h0p  = sub(p, 8192L*1024*2);
  size_t o_h1p  = sub(p, 8192L*4096*2);
  size_t need4 = p;

  size_t need = need1;
  if (need3>need) need=need3;
  if (need4>need) need=need4;
  if (need > ws_size){ dbg_k<<<1,1,0,stream>>>(outF, (float)(need>>20)); return; }

#define WP(o) ((void*)(ws + (o)))
#define BP(o) ((ushort_t*)(ws + (o)))
#define FP(o) ((float*)(ws + (o)))

  // ---- weights -> bf16 transposed ----
  tcvt_k<<<dim3(32,32),256,0,stream>>>(tiW[0], BP(o_tiQw), 1024, 1024);
  tcvt_k<<<dim3(32,32),256,0,stream>>>(tiW[1], BP(o_tiKVw), 1024, 1024);
  tcvt_k<<<dim3(32,32),256,0,stream>>>(tiW[2], BP(o_tiKVw) + 1024L*1024, 1024, 1024);
  tcvt_k<<<dim3(32,32),256,0,stream>>>(tiW[3], BP(o_tiOw), 1024, 1024);
  tcvt_k<<<dim3(32,32),256,0,stream>>>(tpW[0], BP(o_tpQw), 1024, 1024);
  tcvt_k<<<dim3(32,32),256,0,stream>>>(tpW[1], BP(o_tpKVw), 1024, 1024);
  tcvt_k<<<dim3(32,32),256,0,stream>>>(tpW[2], BP(o_tpKVw) + 1024L*1024, 1024, 1024);
  tcvt_k<<<dim3(32,32),256,0,stream>>>(tpW[3], BP(o_tpOw), 1024, 1024);
  tcvt_k<<<dim3(128,32),256,0,stream>>>(iffW1, BP(o_iffW1t), 1024, 4096);
  tcvt_k<<<dim3(32,128),256,0,stream>>>(iffW2, BP(o_iffW2t), 4096, 1024);
  tcvt_k<<<dim3(128,32),256,0,stream>>>(pffW1, BP(o_pffW1t), 1024, 4096);
  tcvt_k<<<dim3(32,128),256,0,stream>>>(pffW2, BP(o_pffW2t), 4096, 1024);
  hipMemcpyAsync(WP(o_bti), (const void*)tib[1], 1024*4, hipMemcpyDeviceToDevice, stream);
  hipMemcpyAsync((void*)(ws+o_bti+1024*4), (const void*)tib[2], 1024*4, hipMemcpyDeviceToDevice, stream);
  hipMemcpyAsync(WP(o_btp), (const void*)tpb[1], 1024*4, hipMemcpyDeviceToDevice, stream);
  hipMemcpyAsync((void*)(ws+o_btp+1024*4), (const void*)tpb[2], 1024*4, hipMemcpyDeviceToDevice, stream);

  // ---- activations -> bf16 ----
  cvt_rows_k<<<2048,256,0,stream>>>(ctx,   BP(o_kv),  8L*256*1024, 256, 1280, 0);
  cvt_rows_k<<<8192,256,0,stream>>>(ptsIn, BP(o_kv),  8L*1024*1024, 1024, 1280, 256);
  cvt_rows_k<<<64,256,0,stream>>>(induc,   BP(o_indb), 64L*1024, 64, 64, 0);
  cvt_rows_k<<<2048,256,0,stream>>>(ctx,   BP(o_kv2), 8L*256*1024, 256, 320, 0);

  // ---- to_induced ----
  gemm(stream,0,0, WP(o_indb), WP(o_tiQw), tib[0], 0, 0, WP(o_Qti),
       64,1024,1024, 1024,1024,0,0,1024, 1,1, 0,0,0,0,0,0,0,0,0,0, 1.f,-1);
  gemm(stream,1,0, WP(o_kv), WP(o_tiKVw), FP(o_bti), 0, 0, WP(o_KVti),
       10240,2048,1024, 1024,1024,0,0,2048, 1,1, 0,0,0,0,0,0,0,0,0,0, 1.f,-1);
  vtrans_k<<<dim3(40,16,8),256,0,stream>>>(BP(o_KVti), BP(o_Vtti), 1280, 2048, 1024);
  fattn_split_k<<<dim3(10,1,128),256,0,stream>>>(BP(o_Qti), BP(o_KVti), BP(o_Vtti),
       FP(o_po), FP(o_pml), 1280, 2048, 2, 0.125f);
  fcomb_k<<<128,256,0,stream>>>(FP(o_po), FP(o_pml), BP(o_attnOti), 10, 64);
  gemm(stream,0,2, WP(o_attnOti), WP(o_tiOw), tib[3], (const void*)induc, WP(o_t1), 0,
       512,1024,1024, 1024,1024,1024,1024,0, 1,1, 0,0,0,0,0,0,0,0,0,0, 1.f,63);
  ln2x_k<<<512,256,0,stream>>>(FP(o_t1), ni_g, ni_b, iff_g, iff_b, FP(o_ind1), 0, BP(o_h0i));
  gemm(stream,0,1, WP(o_h0i), WP(o_iffW1t), iff_b1, 0, 0, WP(o_h1i),
       512,4096,1024, 1024,1024,0,0,4096, 1,1, 0,0,0,0,0,0,0,0,0,0, 1.f,-1);
  gemm(stream,0,2, WP(o_h1i), WP(o_iffW2t), iff_b2, WP(o_ind1), 0, BP(o_kv2) + 262144,
       64,1024,4096, 4096,4096,1024,0,1024, 8,8,
       262144,0, 0,0, 65536,0, 0,0, 327680,0, 1.f,-1);

  // ---- to_points ----
  gemm(stream,2,0, BP(o_kv) + 262144, WP(o_tpQw), tpb[0], 0, 0, WP(o_Qtp),
       1024,1024,1024, 1024,1024,0,0,1024, 8,8,
       1310720,0, 0,0, 0,0, 0,0, 1048576,0, 1.f,-1);
  gemm(stream,0,0, WP(o_kv2), WP(o_tpKVw), FP(o_btp), 0, 0, WP(o_KVtp),
       2560,2048,1024, 1024,1024,0,0,2048, 1,1, 0,0,0,0,0,0,0,0,0,0, 1.f,-1);
  vtrans_k<<<dim3(10,16,8),256,0,stream>>>(BP(o_KVtp), BP(o_Vttp), 320, 2048, 1024);
  fattn_k<true><<<dim3(16,1,128),256,0,stream>>>(BP(o_Qtp), BP(o_KVtp), BP(o_Vttp),
       BP(o_attnOtp), BP(o_P), 320, 2048, 1024, 1024, 0.125f);
  w2ent_k<<<2048,256,0,stream>>>(BP(o_P), FP(o_rowent));
  entfin_k<<<1,256,0,stream>>>(FP(o_rowent), outF + (out_size-1));
  gemm(stream,2,2, WP(o_attnOtp), WP(o_tpOw), tpb[3], (const void*)ptsIn, WP(o_t2), 0,
       8192,1024,1024, 1024,1024,1024,1024,0, 1,1, 0,0,0,0,0,0,0,0,0,0, 1.f,-1);
  ln2x_k<<<8192,256,0,stream>>>(FP(o_t2), np_g, np_b, pff_g, pff_b, 0, BP(o_pts1), BP(o_h0p));
  gemm(stream,1,1, WP(o_h0p), WP(o_pffW1t), pff_b1, 0, 0, WP(o_h1p),
       8192,4096,1024, 1024,1024,0,0,4096, 1,1, 0,0,0,0,0,0,0,0,0,0, 1.f,-1);
  gemm(stream,2,3, WP(o_h1p), WP(o_pffW2t), pff_b2, WP(o_pts1), outF, 0,
       8192,1024,4096, 4096,4096,1024,1024,0, 1,1, 0,0,0,0,0,0,0,0,0,0, 1.f,-1);

#undef WP
#undef BP
#undef FP
}

// Round 14
// 845.467 us; speedup vs baseline: 1.0462x; 1.0462x over previous
//
#include <hip/hip_runtime.h>
#include <hip/hip_bf16.h>
#include <math.h>

typedef unsigned short ushort_t;
typedef __attribute__((ext_vector_type(8))) short short8;
typedef __attribute__((ext_vector_type(4))) float f32x4;

static __device__ __forceinline__ ushort_t f2b(float f){
  union{float f;unsigned u;}a; a.f=f;
  unsigned r = a.u + 0x7fffu + ((a.u>>16)&1u);
  return (ushort_t)(r>>16);
}
static __device__ __forceinline__ float b2f(ushort_t u){
  union{unsigned u;float f;}a; a.u=((unsigned)u)<<16; return a.f;
}
// tanh-form GELU (R10-R12-verified within threshold)
static __device__ __forceinline__ float gelu_f(float v){
  float u = 1.595769122f*v*(1.f + 0.044715f*v*v);
  return v / (1.f + __expf(-u));
}

#define GLDS16(g,l) __builtin_amdgcn_global_load_lds((const __attribute__((address_space(1))) void*)(const void*)(g), (__attribute__((address_space(3))) void*)(void*)(l), 16, 0, 0)

// XCD-chunked (m204 bijective) + stripe-grouped (L2 working-set) block mapping.
static __device__ __forceinline__ void block_map(int GM, int& by, int& bx)
{
  const int gx = gridDim.x, gy = gridDim.y;
  const int nwg = gx*gy;
  const int orig = blockIdx.y*gx + blockIdx.x;
  const int q8 = nwg >> 3, r8 = nwg & 7;
  const int xcd = orig & 7, ii = orig >> 3;
  const int wg = (xcd < r8 ? xcd*(q8+1) : r8*(q8+1) + (xcd-r8)*q8) + ii;
  const int stripe = wg / (GM*gx);
  const int rem = wg - stripe*(GM*gx);
  const int gmEff = min(GM, gy - stripe*GM);
  bx = rem / gmEff;
  by = stripe*GM + (rem - bx*gmEff);
}

// ---------------------------------------------------------------------------
// gemm256 (R9-proven): 256x128 tile, BK=64, 8 waves, 3 buffers, vmcnt(6).
// ---------------------------------------------------------------------------
template<bool GELU, int RES>
__global__ __launch_bounds__(512)
void gemm256(const ushort_t* __restrict__ A, const ushort_t* __restrict__ Bt,
             const float* __restrict__ bias, const void* __restrict__ Res,
             float* __restrict__ Cf, ushort_t* __restrict__ Cb,
             int M, int N, int K, int lda, int ldb, int ldres, int ldcf, int ldcb,
             int nb0,
             long sA0, long sA1, long sB0, long sB1, long sR0, long sR1,
             long sCf0, long sCf1, long sCb0, long sCb1, float scale)
{
  const int z = blockIdx.z;
  const int zb0 = z % nb0, zb1 = z / nb0;
  A  += zb0*sA0 + zb1*sA1;
  Bt += zb0*sB0 + zb1*sB1;
  const float* RpF = 0; const ushort_t* RpB = 0;
  if (RES==1) RpF = (const float*)Res + zb0*sR0 + zb1*sR1;
  if (RES==2) RpB = (const ushort_t*)Res + zb0*sR0 + zb1*sR1;
  if (Cf) Cf += zb0*sCf0 + zb1*sCf1;
  if (Cb) Cb += zb0*sCb0 + zb1*sCb1;

  int by, bx; block_map(4, by, bx);
  const int bm = by*256, bn = bx*128;

  __shared__ __align__(16) char AsR[3][32768];
  __shared__ __align__(16) char BsR[3][16384];

  const int tid = threadIdx.x, lane = tid&63, w = tid>>6;
  const int wr = w>>1, wc = w&1;
  const int lr = lane&15, g16 = (lane>>4)*16;
  const int rxor = (lr&7)<<4;

  f32x4 acc[4][4] = {};

  const int colElem = ((lane&7) ^ ((lane>>3)&7)) << 3;
  const int srRow = w*8 + (lane>>3);
  const ushort_t* pAst[4];
  const ushort_t* pBst[2];
#pragma unroll
  for (int a=0;a<4;a++){
    long r = min((long)(bm + a*64 + srRow), (long)M-1);
    pAst[a] = A + r*lda + colElem;
  }
#pragma unroll
  for (int b=0;b<2;b++){
    long r = min((long)(bn + b*64 + srRow), (long)N-1);
    pBst[b] = Bt + r*ldb + colElem;
  }

  const int aOff = (wr*64 + lr)*128;
  const int bOff = (wc*64 + lr)*128;
  const int NT = K >> 6;

#define STAGE256(Ad, Bd, ktEl) do { \
    GLDS16(pAst[0] + (ktEl), (Ad) + 0*8192 + w*1024); \
    GLDS16(pAst[1] + (ktEl), (Ad) + 1*8192 + w*1024); \
    GLDS16(pAst[2] + (ktEl), (Ad) + 2*8192 + w*1024); \
    GLDS16(pAst[3] + (ktEl), (Ad) + 3*8192 + w*1024); \
    GLDS16(pBst[0] + (ktEl), (Bd) + 0*8192 + w*1024); \
    GLDS16(pBst[1] + (ktEl), (Bd) + 1*8192 + w*1024); \
  } while(0)

  char *Ac = AsR[0], *An1 = AsR[1], *An2 = AsR[2];
  char *Bc = BsR[0], *Bn1 = BsR[1], *Bn2 = BsR[2];

  STAGE256(Ac, Bc, 0);
  if (NT > 1) STAGE256(An1, Bn1, 64);
  asm volatile("s_waitcnt vmcnt(6)" ::: "memory");
  __builtin_amdgcn_s_barrier();

  for (int t=0; t<NT; ++t){
    short8 a0[4], b0[4], a1[4], b1[4];

#pragma unroll
    for (int m=0;m<4;m++) a0[m] = *(const short8*)(Ac + aOff + m*2048 + (g16 ^ rxor));
#pragma unroll
    for (int n=0;n<4;n++) b0[n] = *(const short8*)(Bc + bOff + n*2048 + (g16 ^ rxor));
    if (t+2 < NT) STAGE256(An2, Bn2, (long)(t+2)<<6);
    __builtin_amdgcn_s_barrier();
    asm volatile("s_waitcnt lgkmcnt(0)" ::: "memory");
    __builtin_amdgcn_sched_barrier(0);
    __builtin_amdgcn_s_setprio(1);
#pragma unroll
    for (int m=0;m<4;m++)
#pragma unroll
      for (int n=0;n<4;n++)
        acc[m][n] = __builtin_amdgcn_mfma_f32_16x16x32_bf16(a0[m], b0[n], acc[m][n],0,0,0);
    __builtin_amdgcn_s_setprio(0);
    __builtin_amdgcn_sched_barrier(0);
    __builtin_amdgcn_s_barrier();

#pragma unroll
    for (int m=0;m<4;m++) a1[m] = *(const short8*)(Ac + aOff + m*2048 + ((64 + g16) ^ rxor));
#pragma unroll
    for (int n=0;n<4;n++) b1[n] = *(const short8*)(Bc + bOff + n*2048 + ((64 + g16) ^ rxor));
    __builtin_amdgcn_s_barrier();
    asm volatile("s_waitcnt lgkmcnt(0)" ::: "memory");
    __builtin_amdgcn_sched_barrier(0);
    __builtin_amdgcn_s_setprio(1);
#pragma unroll
    for (int m=0;m<4;m++)
#pragma unroll
      for (int n=0;n<4;n++)
        acc[m][n] = __builtin_amdgcn_mfma_f32_16x16x32_bf16(a1[m], b1[n], acc[m][n],0,0,0);
    __builtin_amdgcn_s_setprio(0);
    __builtin_amdgcn_sched_barrier(0);
    if (t+2 < NT)      { asm volatile("s_waitcnt vmcnt(6)" ::: "memory"); }
    else if (t+1 < NT) { asm volatile("s_waitcnt vmcnt(0)" ::: "memory"); }
    __builtin_amdgcn_s_barrier();
    char* ta = Ac; Ac = An1; An1 = An2; An2 = ta;
    char* tb = Bc; Bc = Bn1; Bn1 = Bn2; Bn2 = tb;
  }
#undef STAGE256

  const int orow = bm + wr*64, ocol = bn + wc*64;
  const int rsub = (lane>>4)*4;
  float bv[4];
#pragma unroll
  for (int n=0;n<4;n++){
    const int col = ocol + n*16 + lr;
    bv[n] = (bias && col < N) ? bias[col] : 0.f;
  }
#pragma unroll
  for (int m=0;m<4;m++){
#pragma unroll
    for (int i=0;i<4;i++){
      const int row = orow + m*16 + rsub + i;
      if (row >= M) continue;
#pragma unroll
      for (int n=0;n<4;n++){
        const int col = ocol + n*16 + lr;
        if (col >= N) continue;
        float v = acc[m][n][i]*scale + bv[n];
        if (GELU) v = gelu_f(v);
        if (RES==1) v += RpF[(long)row*ldres + col];
        if (RES==2) v += b2f(RpB[(long)row*ldres + col]);
        if (Cf) Cf[(long)row*ldcf + col] = v;
        if (Cb) Cb[(long)row*ldcb + col] = f2b(v);
      }
    }
  }
}

// ---------------------------------------------------------------------------
// gemm_sb (R11/R12-proven for huge grids): 128x128 single-buffer, swizzled.
// ---------------------------------------------------------------------------
template<bool GELU, int RES>
__global__ __launch_bounds__(256)
void gemm_sb(const ushort_t* __restrict__ A, const ushort_t* __restrict__ Bt,
             const float* __restrict__ bias, const void* __restrict__ Res,
             float* __restrict__ Cf, ushort_t* __restrict__ Cb,
             int M, int N, int K, int lda, int ldb, int ldres, int ldcf, int ldcb,
             int nb0,
             long sA0, long sA1, long sB0, long sB1, long sR0, long sR1,
             long sCf0, long sCf1, long sCb0, long sCb1, float scale, int resMask)
{
  const int z = blockIdx.z;
  const int b0 = z % nb0, b1 = z / nb0;
  A  += b0*sA0 + b1*sA1;
  Bt += b0*sB0 + b1*sB1;
  const float* RpF = 0; const ushort_t* RpB = 0;
  if (RES==1) RpF = (const float*)Res + b0*sR0 + b1*sR1;
  if (RES==2) RpB = (const ushort_t*)Res + b0*sR0 + b1*sR1;
  if (Cf) Cf += b0*sCf0 + b1*sCf1;
  if (Cb) Cb += b0*sCb0 + b1*sCb1;

  int by, bx; block_map(8, by, bx);
  const int bm = by*128, bn = bx*128;

  __shared__ __align__(16) ushort_t As[4096];
  __shared__ __align__(16) ushort_t Bs[4096];
  const int tid = threadIdx.x, lane = tid&63, wave = tid>>6;
  const int wr = wave>>1, wc = wave&1;

  f32x4 acc[4][4] = {};

  const int c0 = wave*64 + lane;
  const int c1 = c0 + 256;
  const long rA0 = min(bm + (c0>>2), M-1);
  const long rA1 = min(bm + (c1>>2), M-1);
  const long rB0 = min(bn + (c0>>2), N-1);
  const long rB1 = min(bn + (c1>>2), N-1);
  const int ce0 = (((c0&3) ^ ((c0>>3)&3)) << 3);
  const int ce1 = (((c1&3) ^ ((c1>>3)&3)) << 3);
  const ushort_t* pA0 = A + rA0*lda + ce0;
  const ushort_t* pA1 = A + rA1*lda + ce1;
  const ushort_t* pB0 = Bt + rB0*ldb + ce0;
  const ushort_t* pB1 = Bt + rB1*ldb + ce1;
  const int ldsOff = wave*512;

  const int lr = lane&15, g = lane>>4;
  const int lk = ((g ^ ((lr>>1)&3)) << 3);

  for (int kt = 0; kt < K; kt += 32) {
    __syncthreads();
    GLDS16(pA0 + kt, As + ldsOff);
    GLDS16(pA1 + kt, As + 2048 + ldsOff);
    GLDS16(pB0 + kt, Bs + ldsOff);
    GLDS16(pB1 + kt, Bs + 2048 + ldsOff);
    __syncthreads();
    short8 af[4], bfv[4];
#pragma unroll
    for (int m=0;m<4;m++) af[m]  = *(const short8*)(As + (wr*64+m*16+lr)*32 + lk);
#pragma unroll
    for (int n=0;n<4;n++) bfv[n] = *(const short8*)(Bs + (wc*64+n*16+lr)*32 + lk);
#pragma unroll
    for (int m=0;m<4;m++)
#pragma unroll
      for (int n=0;n<4;n++)
        acc[m][n] = __builtin_amdgcn_mfma_f32_16x16x32_bf16(af[m], bfv[n], acc[m][n], 0, 0, 0);
  }

  const int orow = bm + wr*64, ocol = bn + wc*64;
  const int rsub = g*4;
  float bv[4];
#pragma unroll
  for (int n=0;n<4;n++){
    const int col = ocol + n*16 + lr;
    bv[n] = (bias && col < N) ? bias[col] : 0.f;
  }
#pragma unroll
  for (int m=0;m<4;m++){
#pragma unroll
    for (int i=0;i<4;i++){
      const int row = orow + m*16 + rsub + i;
      if (row >= M) continue;
#pragma unroll
      for (int n=0;n<4;n++){
        const int col = ocol + n*16 + lr;
        if (col >= N) continue;
        float v = acc[m][n][i]*scale + bv[n];
        if (GELU) v = gelu_f(v);
        if (RES==1) v += RpF[(long)(row & resMask)*ldres + col];
        if (RES==2) v += b2f(RpB[(long)(row & resMask)*ldres + col]);
        if (Cf) Cf[(long)row*ldcf + col] = v;
        if (Cb) Cb[(long)row*ldcb + col] = f2b(v);
      }
    }
  }
}

// ---------------------------------------------------------------------------
// gemm_bt (double-buffer; small/batched).
// ---------------------------------------------------------------------------
template<bool GELU, int RES>
__global__ __launch_bounds__(256)
void gemm_bt(const ushort_t* __restrict__ A, const ushort_t* __restrict__ Bt,
             const float* __restrict__ bias, const void* __restrict__ Res,
             float* __restrict__ Cf, ushort_t* __restrict__ Cb,
             int M, int N, int K, int lda, int ldb, int ldres, int ldcf, int ldcb,
             int nb0,
             long sA0, long sA1, long sB0, long sB1, long sR0, long sR1,
             long sCf0, long sCf1, long sCb0, long sCb1, float scale, int resMask)
{
  const int z = blockIdx.z;
  const int b0 = z % nb0, b1 = z / nb0;
  A  += b0*sA0 + b1*sA1;
  Bt += b0*sB0 + b1*sB1;
  const float* RpF = 0; const ushort_t* RpB = 0;
  if (RES==1) RpF = (const float*)Res + b0*sR0 + b1*sR1;
  if (RES==2) RpB = (const ushort_t*)Res + b0*sR0 + b1*sR1;
  if (Cf) Cf += b0*sCf0 + b1*sCf1;
  if (Cb) Cb += b0*sCb0 + b1*sCb1;

  int by, bx; block_map(8, by, bx);
  const int bm = by*128, bn = bx*128;

  __shared__ __align__(16) ushort_t As[2][4096];
  __shared__ __align__(16) ushort_t Bs[2][4096];
  const int tid = threadIdx.x, lane = tid&63, wave = tid>>6;
  const int wr = wave>>1, wc = wave&1;

  f32x4 acc[4][4] = {};

  const int c0 = wave*64 + lane;
  const int c1 = c0 + 256;
  const long rA0 = min(bm + (c0>>2), M-1);
  const long rA1 = min(bm + (c1>>2), M-1);
  const long rB0 = min(bn + (c0>>2), N-1);
  const long rB1 = min(bn + (c1>>2), N-1);
  const ushort_t* pA0 = A + rA0*lda + (c0&3)*8;
  const ushort_t* pA1 = A + rA1*lda + (c1&3)*8;
  const ushort_t* pB0 = Bt + rB0*ldb + (c0&3)*8;
  const ushort_t* pB1 = Bt + rB1*ldb + (c1&3)*8;
  const int ldsOff = wave*512;

  const int lr = lane&15, lk = (lane>>4)*8;

#define STAGE(buf, kt) do { \
    GLDS16(pA0 + (kt), &As[buf][ldsOff]); \
    GLDS16(pA1 + (kt), &As[buf][2048 + ldsOff]); \
    GLDS16(pB0 + (kt), &Bs[buf][ldsOff]); \
    GLDS16(pB1 + (kt), &Bs[buf][2048 + ldsOff]); \
  } while(0)

  STAGE(0, 0);
  __syncthreads();
  int cur = 0;
  for (int kt = 0; kt < K; kt += 32) {
    if (kt + 32 < K) STAGE(cur^1, kt+32);
    short8 af[4], bfv[4];
#pragma unroll
    for (int m=0;m<4;m++) af[m]  = *(const short8*)(&As[cur][(wr*64+m*16+lr)*32 + lk]);
#pragma unroll
    for (int n=0;n<4;n++) bfv[n] = *(const short8*)(&Bs[cur][(wc*64+n*16+lr)*32 + lk]);
#pragma unroll
    for (int m=0;m<4;m++)
#pragma unroll
      for (int n=0;n<4;n++)
        acc[m][n] = __builtin_amdgcn_mfma_f32_16x16x32_bf16(af[m], bfv[n], acc[m][n], 0, 0, 0);
    __syncthreads();
    cur ^= 1;
  }
#undef STAGE

  const int orow = bm + wr*64, ocol = bn + wc*64;
  const int rsub = (lane>>4)*4;
  float bv[4];
#pragma unroll
  for (int n=0;n<4;n++){
    const int col = ocol + n*16 + lr;
    bv[n] = (bias && col < N) ? bias[col] : 0.f;
  }
#pragma unroll
  for (int m=0;m<4;m++){
#pragma unroll
    for (int i=0;i<4;i++){
      const int row = orow + m*16 + rsub + i;
      if (row >= M) continue;
#pragma unroll
      for (int n=0;n<4;n++){
        const int col = ocol + n*16 + lr;
        if (col >= N) continue;
        float v = acc[m][n][i]*scale + bv[n];
        if (GELU) v = gelu_f(v);
        if (RES==1) v += RpF[(long)(row & resMask)*ldres + col];
        if (RES==2) v += b2f(RpB[(long)(row & resMask)*ldres + col]);
        if (Cf) Cf[(long)row*ldcf + col] = v;
        if (Cb) Cb[(long)row*ldcb + col] = f2b(v);
      }
    }
  }
}

// ---------------------------------------------------------------------------
// Fused two-pass flash attention (refcheck-proven).
// ---------------------------------------------------------------------------
template<bool WRITEP>
__global__ __launch_bounds__(256)
void fattn_k(const ushort_t* __restrict__ Qb, const ushort_t* __restrict__ KVb,
             const ushort_t* __restrict__ Vtb, ushort_t* __restrict__ Ob,
             ushort_t* __restrict__ Pb,
             int LK, int ldkv, int qRowsPerB, int oRowsPerB, float scale)
{
  const int z = blockIdx.z, b = z >> 4, h = z & 15;
  const int qt = blockIdx.x;
  const int tid = threadIdx.x, lane = tid & 63, wave = tid >> 6;
  const int lr = lane & 15, g = lane >> 4;

  __shared__ __align__(16) ushort_t Kls[64*68];
  __shared__ __align__(16) ushort_t Vtls[64*68];
  __shared__ __align__(16) ushort_t Pls[64*68];

  const long qrow = (long)b*qRowsPerB + qt*64 + wave*16 + lr;
  const short8 aq0 = *(const short8*)(Qb + qrow*1024 + h*64 + g*8);
  const short8 aq1 = *(const short8*)(Qb + qrow*1024 + h*64 + 32 + g*8);

  const ushort_t* Kbase = KVb + (long)b*LK*ldkv + h*64;
  const ushort_t* Vtbase = Vtb + (long)(b*16+h)*64*LK;

  const int ntiles = LK >> 6;
  const int r0 = tid>>3, d0c = (tid&7)*8;
  const int r1 = r0 + 32;

  float m[4] = {-3e30f,-3e30f,-3e30f,-3e30f};
  float l[4] = {0.f,0.f,0.f,0.f};

  for (int t=0; t<ntiles; ++t){
    __syncthreads();
    { short8 v0 = *(const short8*)(Kbase + (long)(t*64 + r0)*ldkv + d0c);
      short8 v1 = *(const short8*)(Kbase + (long)(t*64 + r1)*ldkv + d0c);
      *(short8*)(Kls + r0*68 + d0c) = v0;
      *(short8*)(Kls + r1*68 + d0c) = v1; }
    __syncthreads();
    f32x4 s[4];
#pragma unroll
    for(int n=0;n<4;n++){
      s[n] = (f32x4){0.f,0.f,0.f,0.f};
      short8 bk0 = *(const short8*)(Kls + (n*16+lr)*68 + g*8);
      short8 bk1 = *(const short8*)(Kls + (n*16+lr)*68 + 32 + g*8);
      s[n] = __builtin_amdgcn_mfma_f32_16x16x32_bf16(aq0, bk0, s[n],0,0,0);
      s[n] = __builtin_amdgcn_mfma_f32_16x16x32_bf16(aq1, bk1, s[n],0,0,0);
    }
#pragma unroll
    for(int i=0;i<4;i++){
      float mx = fmaxf(fmaxf(s[0][i],s[1][i]), fmaxf(s[2][i],s[3][i])) * scale;
#pragma unroll
      for(int o2=1;o2<16;o2<<=1) mx = fmaxf(mx, __shfl_xor(mx,o2));
      float mnew = fmaxf(m[i], mx);
      float sum = __expf(s[0][i]*scale-mnew)+__expf(s[1][i]*scale-mnew)
                + __expf(s[2][i]*scale-mnew)+__expf(s[3][i]*scale-mnew);
#pragma unroll
      for(int o2=1;o2<16;o2<<=1) sum += __shfl_xor(sum,o2);
      l[i] = l[i]*__expf(m[i]-mnew) + sum;
      m[i] = mnew;
    }
  }
  float invl[4];
#pragma unroll
  for(int i=0;i<4;i++) invl[i] = 1.f/l[i];

  f32x4 o[4];
#pragma unroll
  for(int n=0;n<4;n++) o[n] = (f32x4){0.f,0.f,0.f,0.f};

  long pbase = 0;
  if (WRITEP) pbase = ((long)(b*16+h)*1024 + qt*64 + wave*16)*320 + lr;

  for (int t=0; t<ntiles; ++t){
    __syncthreads();
    { short8 v0 = *(const short8*)(Kbase + (long)(t*64 + r0)*ldkv + d0c);
      short8 v1 = *(const short8*)(Kbase + (long)(t*64 + r1)*ldkv + d0c);
      short8 w0 = *(const short8*)(Vtbase + (long)r0*LK + t*64 + d0c);
      short8 w1 = *(const short8*)(Vtbase + (long)r1*LK + t*64 + d0c);
      *(short8*)(Kls + r0*68 + d0c) = v0;
      *(short8*)(Kls + r1*68 + d0c) = v1;
      *(short8*)(Vtls + r0*68 + d0c) = w0;
      *(short8*)(Vtls + r1*68 + d0c) = w1; }
    __syncthreads();
    f32x4 s[4];
#pragma unroll
    for(int n=0;n<4;n++){
      s[n] = (f32x4){0.f,0.f,0.f,0.f};
      short8 bk0 = *(const short8*)(Kls + (n*16+lr)*68 + g*8);
      short8 bk1 = *(const short8*)(Kls + (n*16+lr)*68 + 32 + g*8);
      s[n] = __builtin_amdgcn_mfma_f32_16x16x32_bf16(aq0, bk0, s[n],0,0,0);
      s[n] = __builtin_amdgcn_mfma_f32_16x16x32_bf16(aq1, bk1, s[n],0,0,0);
    }
#pragma unroll
    for(int n=0;n<4;n++){
#pragma unroll
      for(int i=0;i<4;i++){
        float e = __expf(s[n][i]*scale - m[i]);
        Pls[(wave*16 + g*4 + i)*68 + n*16 + lr] = f2b(e);
        if (WRITEP) Pb[pbase + (long)(g*4+i)*320 + t*64 + n*16] = f2b(e*invl[i]);
      }
    }
    short8 pa0 = *(const short8*)(Pls + (wave*16+lr)*68 + g*8);
    short8 pa1 = *(const short8*)(Pls + (wave*16+lr)*68 + 32 + g*8);
#pragma unroll
    for(int nd=0; nd<4; nd++){
      short8 vb0 = *(const short8*)(Vtls + (nd*16+lr)*68 + g*8);
      short8 vb1 = *(const short8*)(Vtls + (nd*16+lr)*68 + 32 + g*8);
      o[nd] = __builtin_amdgcn_mfma_f32_16x16x32_bf16(pa0, vb0, o[nd],0,0,0);
      o[nd] = __builtin_amdgcn_mfma_f32_16x16x32_bf16(pa1, vb1, o[nd],0,0,0);
    }
  }
  const long orow0 = (long)b*oRowsPerB + qt*64 + wave*16 + g*4;
#pragma unroll
  for(int nd=0;nd<4;nd++)
#pragma unroll
    for(int i=0;i<4;i++)
      Ob[(orow0+i)*1024 + h*64 + nd*16 + lr] = f2b(o[nd][i]*invl[i]);
}

__global__ __launch_bounds__(256)
void tcvt_k(const float* __restrict__ src, ushort_t* __restrict__ dst, int R, int C)
{
  __shared__ float t[32][33];
  int c0 = blockIdx.x*32, r0 = blockIdx.y*32;
  int tx = threadIdx.x & 31, ty = threadIdx.x >> 5;
  for (int i=ty;i<32;i+=8){ int r=r0+i, c=c0+tx; t[i][tx] = (r<R && c<C) ? src[(long)r*C + c] : 0.f; }
  __syncthreads();
  for (int i=ty;i<32;i+=8){ int c=c0+i, r=r0+tx; if (c<C && r<R) dst[(long)c*R + r] = f2b(t[tx][i]); }
}

__global__ __launch_bounds__(256)
void cvt_rows_k(const float* __restrict__ src, ushort_t* __restrict__ dst,
                long total, int R, long dstBS, long dstRO)
{
  long e = ((long)blockIdx.x*256 + threadIdx.x)*4;
  if (e >= total) return;
  long rc = e >> 10; int c = (int)(e & 1023);
  int r = (int)(rc % R); long b = rc / R;
  float4 v = *(const float4*)(src + e);
  ushort4 o; o.x=f2b(v.x); o.y=f2b(v.y); o.z=f2b(v.z); o.w=f2b(v.w);
  *(ushort4*)(dst + (b*dstBS + dstRO + r)*1024 + c) = o;
}

// ctx (8x256x1024 fp32) -> kv rows [0,256) (BS 1280) AND kv2 rows [0,256) (BS 320)
__global__ __launch_bounds__(256)
void cvt_ctx2_k(const float* __restrict__ src, ushort_t* __restrict__ d1, ushort_t* __restrict__ d2)
{
  long e = ((long)blockIdx.x*256 + threadIdx.x)*4;   // grid covers 8*256*1024
  long rc = e >> 10; int c = (int)(e & 1023);
  int r = (int)(rc & 255); long b = rc >> 8;
  float4 v = *(const float4*)(src + e);
  ushort4 o; o.x=f2b(v.x); o.y=f2b(v.y); o.z=f2b(v.z); o.w=f2b(v.w);
  *(ushort4*)(d1 + (b*1280 + r)*1024 + c) = o;
  *(ushort4*)(d2 + (b*320  + r)*1024 + c) = o;
}

__global__ __launch_bounds__(256)
void vtrans_k(const ushort_t* __restrict__ V, ushort_t* __restrict__ Vt,
              int Lk, int ldv, int coloff)
{
  int b = blockIdx.z, h = blockIdx.y, k0 = blockIdx.x*32;
  __shared__ ushort_t t[32][65];
  int tx = threadIdx.x & 63, ty = threadIdx.x >> 6;
  for (int i=ty;i<32;i+=4) t[i][tx] = V[((long)b*Lk + k0 + i)*ldv + coloff + h*64 + tx];
  __syncthreads();
  int kk = threadIdx.x & 31, n0 = threadIdx.x >> 5;
  for (int n=n0;n<64;n+=8) Vt[((long)(b*16+h)*64 + n)*Lk + k0 + kk] = t[kk][n];
}

__global__ __launch_bounds__(256)
void ln2x_k(const float* __restrict__ x,
            const float* __restrict__ g1, const float* __restrict__ b1,
            const float* __restrict__ g2, const float* __restrict__ b2,
            float* __restrict__ y1f, ushort_t* __restrict__ y1b, ushort_t* __restrict__ y2b)
{
  const long row = blockIdx.x;
  int tid = threadIdx.x, lane = tid&63, wave = tid>>6;
  __shared__ float red[8], red2[8];
  float4 v = ((const float4*)(x + row*1024))[tid];
  float s = v.x+v.y+v.z+v.w;
  for (int o=32;o;o>>=1) s += __shfl_down(s,o);
  if (lane==0) red[wave]=s;
  __syncthreads();
  float mean = (red[0]+red[1]+red[2]+red[3])*(1.f/1024.f);
  float d0=v.x-mean, d1=v.y-mean, d2=v.z-mean, d3=v.w-mean;
  float q = d0*d0+d1*d1+d2*d2+d3*d3;
  for (int o=32;o;o>>=1) q += __shfl_down(q,o);
  if (lane==0) red[4+wave]=q;
  __syncthreads();
  float var = (red[4]+red[5]+red[6]+red[7])*(1.f/1024.f);
  float rs = rsqrtf(var+1e-5f);
  float4 gg=((const float4*)g1)[tid], bb=((const float4*)b1)[tid];
  float y0=d0*rs*gg.x+bb.x, y1v=d1*rs*gg.y+bb.y, y2v=d2*rs*gg.z+bb.z, y3=d3*rs*gg.w+bb.w;
  if (y1f) ((float4*)(y1f+row*1024))[tid] = make_float4(y0,y1v,y2v,y3);
  if (y1b){ ushort4 o4; o4.x=f2b(y0); o4.y=f2b(y1v); o4.z=f2b(y2v); o4.w=f2b(y3);
            ((ushort4*)(y1b+row*1024))[tid]=o4; }
  float s2 = y0+y1v+y2v+y3;
  for (int o=32;o;o>>=1) s2 += __shfl_down(s2,o);
  if (lane==0) red2[wave]=s2;
  __syncthreads();
  float mean2 = (red2[0]+red2[1]+red2[2]+red2[3])*(1.f/1024.f);
  float e0=y0-mean2,e1=y1v-mean2,e2=y2v-mean2,e3=y3-mean2;
  float q2 = e0*e0+e1*e1+e2*e2+e3*e3;
  for (int o=32;o;o>>=1) q2 += __shfl_down(q2,o);
  if (lane==0) red2[4+wave]=q2;
  __syncthreads();
  float var2 = (red2[4]+red2[5]+red2[6]+red2[7])*(1.f/1024.f);
  float rs2 = rsqrtf(var2+1e-5f);
  float4 g2v=((const float4*)g2)[tid], b2v=((const float4*)b2)[tid];
  ushort4 o4;
  o4.x=f2b(e0*rs2*g2v.x+b2v.x); o4.y=f2b(e1*rs2*g2v.y+b2v.y);
  o4.z=f2b(e2*rs2*g2v.z+b2v.z); o4.w=f2b(e3*rs2*g2v.w+b2v.w);
  ((ushort4*)(y2b+row*1024))[tid]=o4;
}

__global__ __launch_bounds__(256)
void w2ent_k(const ushort_t* __restrict__ P, float* __restrict__ rowent)
{
  int wid = (int)((blockIdx.x*256 + threadIdx.x) >> 6);
  int lane = threadIdx.x & 63;
  int b = wid >> 10, q = wid & 1023;
  const ushort_t* base = P + ((long)(b*16)*1024 + q)*320;
  float acc = 0.f;
#pragma unroll
  for (int j=0;j<5;j++){
    int k = j*64 + lane;
    float s = 0.f;
#pragma unroll
    for (int h=0;h<16;h++) s += b2f(base[(long)h*327680 + k]);
    float p = fmaxf(s*(1.f/16.f), 1e-8f);
    acc += p*__logf(p);
  }
  for (int o=32;o;o>>=1) acc += __shfl_down(acc, o);
  if (lane==0) rowent[wid] = acc;
}

__global__ __launch_bounds__(256)
void entfin_k(const float* __restrict__ rowent, float* __restrict__ out)
{
  float s = 0.f;
  for (int i=threadIdx.x;i<8192;i+=256) s += rowent[i];
  __shared__ float red[4];
  for (int o=32;o;o>>=1) s += __shfl_down(s,o);
  if ((threadIdx.x&63)==0) red[threadIdx.x>>6]=s;
  __syncthreads();
  if (threadIdx.x==0) out[0] = -(red[0]+red[1]+red[2]+red[3]) * (1.f/8192.f);
}

__global__ void dbg_k(float* out, float a){ out[0] = -12345.f; out[1] = a; }

// ---------------------------------------------------------------------------
// variant: 0 = gemm_bt (db), 1 = gemm_sb, 2 = gemm256
static void gemm(hipStream_t s, int variant, int mode,
                 const void* A, const void* Bt, const float* bias, const void* Res,
                 void* Cf, void* Cb,
                 int M, int N, int K, int lda, int ldb, int ldres, int ldcf, int ldcb,
                 int nz, int nb0,
                 long sA0, long sA1, long sB0, long sB1, long sR0, long sR1,
                 long sCf0, long sCf1, long sCb0, long sCb1, float scale, int resMask)
{
#define ARGS (const ushort_t*)A,(const ushort_t*)Bt,bias,Res,(float*)Cf,(ushort_t*)Cb,M,N,K,lda,ldb,ldres,ldcf,ldcb,nb0,sA0,sA1,sB0,sB1,sR0,sR1,sCf0,sCf1,sCb0,sCb1,scale,resMask
#define ARGS6 (const ushort_t*)A,(const ushort_t*)Bt,bias,Res,(float*)Cf,(ushort_t*)Cb,M,N,K,lda,ldb,ldres,ldcf,ldcb,nb0,sA0,sA1,sB0,sB1,sR0,sR1,sCf0,sCf1,sCb0,sCb1,scale
  if (variant == 2){
    dim3 g((N+127)/128, (M+255)/256, nz), b(512,1,1);
    if      (mode == 1) gemm256<true ,0><<<g,b,0,s>>>(ARGS6);
    else if (mode == 2) gemm256<false,1><<<g,b,0,s>>>(ARGS6);
    else if (mode == 3) gemm256<false,2><<<g,b,0,s>>>(ARGS6);
    else                gemm256<false,0><<<g,b,0,s>>>(ARGS6);
  } else if (variant == 1){
    dim3 g((N+127)/128, (M+127)/128, nz), b(256,1,1);
    if      (mode == 1) gemm_sb<true ,0><<<g,b,0,s>>>(ARGS);
    else if (mode == 2) gemm_sb<false,1><<<g,b,0,s>>>(ARGS);
    else if (mode == 3) gemm_sb<false,2><<<g,b,0,s>>>(ARGS);
    else                gemm_sb<false,0><<<g,b,0,s>>>(ARGS);
  } else {
    dim3 g((N+127)/128, (M+127)/128, nz), b(256,1,1);
    if      (mode == 1) gemm_bt<true ,0><<<g,b,0,s>>>(ARGS);
    else if (mode == 2) gemm_bt<false,1><<<g,b,0,s>>>(ARGS);
    else if (mode == 3) gemm_bt<false,2><<<g,b,0,s>>>(ARGS);
    else                gemm_bt<false,0><<<g,b,0,s>>>(ARGS);
  }
#undef ARGS
#undef ARGS6
}

extern "C" void kernel_launch(void* const* d_in, const int* in_sizes, int n_in,
                              void* d_out, int out_size, void* d_ws, size_t ws_size,
                              hipStream_t stream)
{
  const float* ptsIn = (const float*)d_in[0];
  const float* ctx   = (const float*)d_in[1];
  const float* induc = (const float*)d_in[2];
  const float* tiW[4]={(const float*)d_in[3],(const float*)d_in[4],(const float*)d_in[5],(const float*)d_in[6]};
  const float* tib[4]={(const float*)d_in[7],(const float*)d_in[8],(const float*)d_in[9],(const float*)d_in[10]};
  const float* tpW[4]={(const float*)d_in[11],(const float*)d_in[12],(const float*)d_in[13],(const float*)d_in[14]};
  const float* tpb[4]={(const float*)d_in[15],(const float*)d_in[16],(const float*)d_in[17],(const float*)d_in[18]};
  const float* iff_g=(const float*)d_in[19]; const float* iff_b=(const float*)d_in[20];
  const float* iffW1=(const float*)d_in[21]; const float* iff_b1=(const float*)d_in[22];
  const float* iffW2=(const float*)d_in[23]; const float* iff_b2=(const float*)d_in[24];
  const float* pff_g=(const float*)d_in[25]; const float* pff_b=(const float*)d_in[26];
  const float* pffW1=(const float*)d_in[27]; const float* pff_b1=(const float*)d_in[28];
  const float* pffW2=(const float*)d_in[29]; const float* pff_b2=(const float*)d_in[30];
  const float* ni_g=(const float*)d_in[31]; const float* ni_b=(const float*)d_in[32];
  const float* np_g=(const float*)d_in[33]; const float* np_b=(const float*)d_in[34];
  float* outF = (float*)d_out;

  char* ws = (char*)d_ws;
  size_t off = 0;
  auto alloc = [&](size_t bytes){ off=(off+255)&~(size_t)255; size_t o=off; off+=bytes; return o; };
  auto sub = [&](size_t& pp, size_t bytes){ pp=(pp+255)&~(size_t)255; size_t o=pp; pp+=bytes; return o; };

  // ---- persistent ----
  size_t o_tiQw  = alloc(1024L*1024*2);
  size_t o_tiKVw = alloc(2048L*1024*2);
  size_t o_tiOw  = alloc(1024L*1024*2);
  size_t o_tpQw  = alloc(1024L*1024*2);
  size_t o_tpKVw = alloc(2048L*1024*2);
  size_t o_tpOw  = alloc(1024L*1024*2);
  size_t o_iffW1t = alloc(4096L*1024*2);
  size_t o_iffW2t = alloc(4096L*1024*2);
  size_t o_pffW1t = alloc(4096L*1024*2);
  size_t o_pffW2t = alloc(4096L*1024*2);
  size_t o_bti  = alloc(2048*4);
  size_t o_btp  = alloc(2048*4);
  size_t o_indb = alloc(64L*1024*2);
  size_t o_kv   = alloc(10240L*1024*2);
  size_t o_kv2  = alloc(2560L*1024*2);
  size_t o_rowent = alloc(8192*4);
  off=(off+255)&~(size_t)255;
  size_t arena = off;

  // ---- ti phase ----
  size_t p = arena;
  size_t o_Qti     = sub(p, 64L*1024*2);
  size_t o_KVti    = sub(p, 10240L*2048*2);
  size_t o_Vtti    = sub(p, 8192L*1280*2);
  size_t o_attnOti = sub(p, 512L*1024*2);
  size_t o_t1      = sub(p, 512L*1024*4);
  size_t o_ind1    = sub(p, 512L*1024*4);
  size_t o_h0i     = sub(p, 512L*1024*2);
  size_t o_h1i     = sub(p, 512L*4096*2);
  size_t need1 = p;
  // ---- tp phase ----
  p = arena;
  size_t o_attnOtp = sub(p, 8192L*1024*2);
  size_t shared = p;
  size_t o_Qtp  = sub(p, 8192L*1024*2);
  size_t o_KVtp = sub(p, 2560L*2048*2);
  size_t o_Vttp = sub(p, 8192L*320*2);
  size_t o_P    = sub(p, 8L*16*1024*320*2);
  size_t need3 = p;
  p = shared;
  size_t o_t2   = sub(p, 8192L*1024*4);
  size_t o_pts1 = sub(p, 8192L*1024*2);
  size_t o_h0p  = sub(p, 8192L*1024*2);
  size_t o_h1p  = sub(p, 8192L*4096*2);
  size_t need4 = p;

  size_t need = need1;
  if (need3>need) need=need3;
  if (need4>need) need=need4;
  if (need > ws_size){ dbg_k<<<1,1,0,stream>>>(outF, (float)(need>>20)); return; }

#define WP(o) ((void*)(ws + (o)))
#define BP(o) ((ushort_t*)(ws + (o)))
#define FP(o) ((float*)(ws + (o)))

  // ---- weights -> bf16 transposed ----
  tcvt_k<<<dim3(32,32),256,0,stream>>>(tiW[0], BP(o_tiQw), 1024, 1024);
  tcvt_k<<<dim3(32,32),256,0,stream>>>(tiW[1], BP(o_tiKVw), 1024, 1024);
  tcvt_k<<<dim3(32,32),256,0,stream>>>(tiW[2], BP(o_tiKVw) + 1024L*1024, 1024, 1024);
  tcvt_k<<<dim3(32,32),256,0,stream>>>(tiW[3], BP(o_tiOw), 1024, 1024);
  tcvt_k<<<dim3(32,32),256,0,stream>>>(tpW[0], BP(o_tpQw), 1024, 1024);
  tcvt_k<<<dim3(32,32),256,0,stream>>>(tpW[1], BP(o_tpKVw), 1024, 1024);
  tcvt_k<<<dim3(32,32),256,0,stream>>>(tpW[2], BP(o_tpKVw) + 1024L*1024, 1024, 1024);
  tcvt_k<<<dim3(32,32),256,0,stream>>>(tpW[3], BP(o_tpOw), 1024, 1024);
  tcvt_k<<<dim3(128,32),256,0,stream>>>(iffW1, BP(o_iffW1t), 1024, 4096);
  tcvt_k<<<dim3(32,128),256,0,stream>>>(iffW2, BP(o_iffW2t), 4096, 1024);
  tcvt_k<<<dim3(128,32),256,0,stream>>>(pffW1, BP(o_pffW1t), 1024, 4096);
  tcvt_k<<<dim3(32,128),256,0,stream>>>(pffW2, BP(o_pffW2t), 4096, 1024);
  hipMemcpyAsync(WP(o_bti), (const void*)tib[1], 1024*4, hipMemcpyDeviceToDevice, stream);
  hipMemcpyAsync((void*)(ws+o_bti+1024*4), (const void*)tib[2], 1024*4, hipMemcpyDeviceToDevice, stream);
  hipMemcpyAsync(WP(o_btp), (const void*)tpb[1], 1024*4, hipMemcpyDeviceToDevice, stream);
  hipMemcpyAsync((void*)(ws+o_btp+1024*4), (const void*)tpb[2], 1024*4, hipMemcpyDeviceToDevice, stream);

  // ---- activations -> bf16 (ctx read once, written to kv AND kv2) ----
  cvt_ctx2_k<<<2048,256,0,stream>>>(ctx, BP(o_kv), BP(o_kv2));
  cvt_rows_k<<<8192,256,0,stream>>>(ptsIn, BP(o_kv),  8L*1024*1024, 1024, 1280, 256);
  cvt_rows_k<<<64,256,0,stream>>>(induc,   BP(o_indb), 64L*1024, 64, 64, 0);

  // ---- to_induced ----
  gemm(stream,0,0, WP(o_indb), WP(o_tiQw), tib[0], 0, 0, WP(o_Qti),
       64,1024,1024, 1024,1024,0,0,1024, 1,1, 0,0,0,0,0,0,0,0,0,0, 1.f,-1);
  gemm(stream,1,0, WP(o_kv), WP(o_tiKVw), FP(o_bti), 0, 0, WP(o_KVti),
       10240,2048,1024, 1024,1024,0,0,2048, 1,1, 0,0,0,0,0,0,0,0,0,0, 1.f,-1);
  vtrans_k<<<dim3(40,16,8),256,0,stream>>>(BP(o_KVti), BP(o_Vtti), 1280, 2048, 1024);
  fattn_k<false><<<dim3(1,1,128),256,0,stream>>>(BP(o_Qti), BP(o_KVti), BP(o_Vtti),
       BP(o_attnOti), (ushort_t*)0, 1280, 2048, 0, 64, 0.125f);
  gemm(stream,0,2, WP(o_attnOti), WP(o_tiOw), tib[3], (const void*)induc, WP(o_t1), 0,
       512,1024,1024, 1024,1024,1024,1024,0, 1,1, 0,0,0,0,0,0,0,0,0,0, 1.f,63);
  ln2x_k<<<512,256,0,stream>>>(FP(o_t1), ni_g, ni_b, iff_g, iff_b, FP(o_ind1), 0, BP(o_h0i));
  gemm(stream,0,1, WP(o_h0i), WP(o_iffW1t), iff_b1, 0, 0, WP(o_h1i),
       512,4096,1024, 1024,1024,0,0,4096, 1,1, 0,0,0,0,0,0,0,0,0,0, 1.f,-1);
  gemm(stream,0,2, WP(o_h1i), WP(o_iffW2t), iff_b2, WP(o_ind1), 0, BP(o_kv2) + 262144,
       64,1024,4096, 4096,4096,1024,0,1024, 8,8,
       262144,0, 0,0, 65536,0, 0,0, 327680,0, 1.f,-1);

  // ---- to_points ----
  gemm(stream,2,0, BP(o_kv) + 262144, WP(o_tpQw), tpb[0], 0, 0, WP(o_Qtp),
       1024,1024,1024, 1024,1024,0,0,1024, 8,8,
       1310720,0, 0,0, 0,0, 0,0, 1048576,0, 1.f,-1);
  gemm(stream,0,0, WP(o_kv2), WP(o_tpKVw), FP(o_btp), 0, 0, WP(o_KVtp),
       2560,2048,1024, 1024,1024,0,0,2048, 1,1, 0,0,0,0,0,0,0,0,0,0, 1.f,-1);
  vtrans_k<<<dim3(10,16,8),256,0,stream>>>(BP(o_KVtp), BP(o_Vttp), 320, 2048, 1024);
  fattn_k<true><<<dim3(16,1,128),256,0,stream>>>(BP(o_Qtp), BP(o_KVtp), BP(o_Vttp),
       BP(o_attnOtp), BP(o_P), 320, 2048, 1024, 1024, 0.125f);
  w2ent_k<<<2048,256,0,stream>>>(BP(o_P), FP(o_rowent));
  entfin_k<<<1,256,0,stream>>>(FP(o_rowent), outF + (out_size-1));
  gemm(stream,2,2, WP(o_attnOtp), WP(o_tpOw), tpb[3], (const void*)ptsIn, WP(o_t2), 0,
       8192,1024,1024, 1024,1024,1024,1024,0, 1,1, 0,0,0,0,0,0,0,0,0,0, 1.f,-1);
  ln2x_k<<<8192,256,0,stream>>>(FP(o_t2), np_g, np_b, pff_g, pff_b, 0, BP(o_pts1), BP(o_h0p));
  gemm(stream,1,1, WP(o_h0p), WP(o_pffW1t), pff_b1, 0, 0, WP(o_h1p),
       8192,4096,1024, 1024,1024,0,0,4096, 1,1, 0,0,0,0,0,0,0,0,0,0, 1.f,-1);
  gemm(stream,2,3, WP(o_h1p), WP(o_pffW2t), pff_b2, WP(o_pts1), outF, 0,
       8192,1024,4096, 4096,4096,1024,1024,0, 1,1, 0,0,0,0,0,0,0,0,0,0, 1.f,-1);

#undef WP
#undef BP
#undef FP
}

// Round 15
// 827.192 us; speedup vs baseline: 1.0693x; 1.0221x over previous
//
#include <hip/hip_runtime.h>
#include <hip/hip_bf16.h>
#include <math.h>

typedef unsigned short ushort_t;
typedef __attribute__((ext_vector_type(8))) short short8;
typedef __attribute__((ext_vector_type(4))) float f32x4;

static __device__ __forceinline__ ushort_t f2b(float f){
  union{float f;unsigned u;}a; a.f=f;
  unsigned r = a.u + 0x7fffu + ((a.u>>16)&1u);
  return (ushort_t)(r>>16);
}
static __device__ __forceinline__ float b2f(ushort_t u){
  union{unsigned u;float f;}a; a.u=((unsigned)u)<<16; return a.f;
}
// tanh-form GELU (R10-R14-verified within threshold)
static __device__ __forceinline__ float gelu_f(float v){
  float u = 1.595769122f*v*(1.f + 0.044715f*v*v);
  return v / (1.f + __expf(-u));
}

#define GLDS16(g,l) __builtin_amdgcn_global_load_lds((const __attribute__((address_space(1))) void*)(const void*)(g), (__attribute__((address_space(3))) void*)(void*)(l), 16, 0, 0)

// XCD-chunked (m204 bijective) + stripe-grouped (L2 working-set) block mapping.
static __device__ __forceinline__ void block_map(int GM, int& by, int& bx)
{
  const int gx = gridDim.x, gy = gridDim.y;
  const int nwg = gx*gy;
  const int orig = blockIdx.y*gx + blockIdx.x;
  const int q8 = nwg >> 3, r8 = nwg & 7;
  const int xcd = orig & 7, ii = orig >> 3;
  const int wg = (xcd < r8 ? xcd*(q8+1) : r8*(q8+1) + (xcd-r8)*q8) + ii;
  const int stripe = wg / (GM*gx);
  const int rem = wg - stripe*(GM*gx);
  const int gmEff = min(GM, gy - stripe*GM);
  bx = rem / gmEff;
  by = stripe*GM + (rem - bx*gmEff);
}

// ---------------------------------------------------------------------------
// gemm256 (R9-proven): 256x128 tile, BK=64, 8 waves, 3 buffers, vmcnt(6).
// ---------------------------------------------------------------------------
template<bool GELU, int RES>
__global__ __launch_bounds__(512)
void gemm256(const ushort_t* __restrict__ A, const ushort_t* __restrict__ Bt,
             const float* __restrict__ bias, const void* __restrict__ Res,
             float* __restrict__ Cf, ushort_t* __restrict__ Cb,
             int M, int N, int K, int lda, int ldb, int ldres, int ldcf, int ldcb,
             int nb0,
             long sA0, long sA1, long sB0, long sB1, long sR0, long sR1,
             long sCf0, long sCf1, long sCb0, long sCb1, float scale)
{
  const int z = blockIdx.z;
  const int zb0 = z % nb0, zb1 = z / nb0;
  A  += zb0*sA0 + zb1*sA1;
  Bt += zb0*sB0 + zb1*sB1;
  const float* RpF = 0; const ushort_t* RpB = 0;
  if (RES==1) RpF = (const float*)Res + zb0*sR0 + zb1*sR1;
  if (RES==2) RpB = (const ushort_t*)Res + zb0*sR0 + zb1*sR1;
  if (Cf) Cf += zb0*sCf0 + zb1*sCf1;
  if (Cb) Cb += zb0*sCb0 + zb1*sCb1;

  int by, bx; block_map(4, by, bx);
  const int bm = by*256, bn = bx*128;

  __shared__ __align__(16) char AsR[3][32768];
  __shared__ __align__(16) char BsR[3][16384];

  const int tid = threadIdx.x, lane = tid&63, w = tid>>6;
  const int wr = w>>1, wc = w&1;
  const int lr = lane&15, g16 = (lane>>4)*16;
  const int rxor = (lr&7)<<4;

  f32x4 acc[4][4] = {};

  const int colElem = ((lane&7) ^ ((lane>>3)&7)) << 3;
  const int srRow = w*8 + (lane>>3);
  const ushort_t* pAst[4];
  const ushort_t* pBst[2];
#pragma unroll
  for (int a=0;a<4;a++){
    long r = min((long)(bm + a*64 + srRow), (long)M-1);
    pAst[a] = A + r*lda + colElem;
  }
#pragma unroll
  for (int b=0;b<2;b++){
    long r = min((long)(bn + b*64 + srRow), (long)N-1);
    pBst[b] = Bt + r*ldb + colElem;
  }

  const int aOff = (wr*64 + lr)*128;
  const int bOff = (wc*64 + lr)*128;
  const int NT = K >> 6;

#define STAGE256(Ad, Bd, ktEl) do { \
    GLDS16(pAst[0] + (ktEl), (Ad) + 0*8192 + w*1024); \
    GLDS16(pAst[1] + (ktEl), (Ad) + 1*8192 + w*1024); \
    GLDS16(pAst[2] + (ktEl), (Ad) + 2*8192 + w*1024); \
    GLDS16(pAst[3] + (ktEl), (Ad) + 3*8192 + w*1024); \
    GLDS16(pBst[0] + (ktEl), (Bd) + 0*8192 + w*1024); \
    GLDS16(pBst[1] + (ktEl), (Bd) + 1*8192 + w*1024); \
  } while(0)

  char *Ac = AsR[0], *An1 = AsR[1], *An2 = AsR[2];
  char *Bc = BsR[0], *Bn1 = BsR[1], *Bn2 = BsR[2];

  STAGE256(Ac, Bc, 0);
  if (NT > 1) STAGE256(An1, Bn1, 64);
  asm volatile("s_waitcnt vmcnt(6)" ::: "memory");
  __builtin_amdgcn_s_barrier();

  for (int t=0; t<NT; ++t){
    short8 a0[4], b0[4], a1[4], b1[4];

#pragma unroll
    for (int m=0;m<4;m++) a0[m] = *(const short8*)(Ac + aOff + m*2048 + (g16 ^ rxor));
#pragma unroll
    for (int n=0;n<4;n++) b0[n] = *(const short8*)(Bc + bOff + n*2048 + (g16 ^ rxor));
    if (t+2 < NT) STAGE256(An2, Bn2, (long)(t+2)<<6);
    __builtin_amdgcn_s_barrier();
    asm volatile("s_waitcnt lgkmcnt(0)" ::: "memory");
    __builtin_amdgcn_sched_barrier(0);
    __builtin_amdgcn_s_setprio(1);
#pragma unroll
    for (int m=0;m<4;m++)
#pragma unroll
      for (int n=0;n<4;n++)
        acc[m][n] = __builtin_amdgcn_mfma_f32_16x16x32_bf16(a0[m], b0[n], acc[m][n],0,0,0);
    __builtin_amdgcn_s_setprio(0);
    __builtin_amdgcn_sched_barrier(0);
    __builtin_amdgcn_s_barrier();

#pragma unroll
    for (int m=0;m<4;m++) a1[m] = *(const short8*)(Ac + aOff + m*2048 + ((64 + g16) ^ rxor));
#pragma unroll
    for (int n=0;n<4;n++) b1[n] = *(const short8*)(Bc + bOff + n*2048 + ((64 + g16) ^ rxor));
    __builtin_amdgcn_s_barrier();
    asm volatile("s_waitcnt lgkmcnt(0)" ::: "memory");
    __builtin_amdgcn_sched_barrier(0);
    __builtin_amdgcn_s_setprio(1);
#pragma unroll
    for (int m=0;m<4;m++)
#pragma unroll
      for (int n=0;n<4;n++)
        acc[m][n] = __builtin_amdgcn_mfma_f32_16x16x32_bf16(a1[m], b1[n], acc[m][n],0,0,0);
    __builtin_amdgcn_s_setprio(0);
    __builtin_amdgcn_sched_barrier(0);
    if (t+2 < NT)      { asm volatile("s_waitcnt vmcnt(6)" ::: "memory"); }
    else if (t+1 < NT) { asm volatile("s_waitcnt vmcnt(0)" ::: "memory"); }
    __builtin_amdgcn_s_barrier();
    char* ta = Ac; Ac = An1; An1 = An2; An2 = ta;
    char* tb = Bc; Bc = Bn1; Bn1 = Bn2; Bn2 = tb;
  }
#undef STAGE256

  const int orow = bm + wr*64, ocol = bn + wc*64;
  const int rsub = (lane>>4)*4;
  float bv[4];
#pragma unroll
  for (int n=0;n<4;n++){
    const int col = ocol + n*16 + lr;
    bv[n] = (bias && col < N) ? bias[col] : 0.f;
  }
#pragma unroll
  for (int m=0;m<4;m++){
#pragma unroll
    for (int i=0;i<4;i++){
      const int row = orow + m*16 + rsub + i;
      if (row >= M) continue;
#pragma unroll
      for (int n=0;n<4;n++){
        const int col = ocol + n*16 + lr;
        if (col >= N) continue;
        float v = acc[m][n][i]*scale + bv[n];
        if (GELU) v = gelu_f(v);
        if (RES==1) v += RpF[(long)row*ldres + col];
        if (RES==2) v += b2f(RpB[(long)row*ldres + col]);
        if (Cf) Cf[(long)row*ldcf + col] = v;
        if (Cb) Cb[(long)row*ldcb + col] = f2b(v);
      }
    }
  }
}

// ---------------------------------------------------------------------------
// gemm_sb (R15: BK=64 single-buffer): 128x128 tile, 32 KB LDS, 4 waves.
// Half the barrier-drain crossings per K vs BK=32. Swizzle = R6-verified pair:
// stage colElem 8*((L&7)^((L>>3)&7)); read field ((g+4s)^(lr&7))<<4.
// ---------------------------------------------------------------------------
template<bool GELU, int RES>
__global__ __launch_bounds__(256)
void gemm_sb(const ushort_t* __restrict__ A, const ushort_t* __restrict__ Bt,
             const float* __restrict__ bias, const void* __restrict__ Res,
             float* __restrict__ Cf, ushort_t* __restrict__ Cb,
             int M, int N, int K, int lda, int ldb, int ldres, int ldcf, int ldcb,
             int nb0,
             long sA0, long sA1, long sB0, long sB1, long sR0, long sR1,
             long sCf0, long sCf1, long sCb0, long sCb1, float scale, int resMask)
{
  const int z = blockIdx.z;
  const int b0 = z % nb0, b1 = z / nb0;
  A  += b0*sA0 + b1*sA1;
  Bt += b0*sB0 + b1*sB1;
  const float* RpF = 0; const ushort_t* RpB = 0;
  if (RES==1) RpF = (const float*)Res + b0*sR0 + b1*sR1;
  if (RES==2) RpB = (const ushort_t*)Res + b0*sR0 + b1*sR1;
  if (Cf) Cf += b0*sCf0 + b1*sCf1;
  if (Cb) Cb += b0*sCb0 + b1*sCb1;

  int by, bx; block_map(8, by, bx);
  const int bm = by*128, bn = bx*128;

  __shared__ __align__(16) char As[16384];   // 128 rows x 128 B (BK=64), swizzled
  __shared__ __align__(16) char Bs[16384];
  const int tid = threadIdx.x, lane = tid&63, wave = tid>>6;
  const int wr = wave>>1, wc = wave&1;

  f32x4 acc[4][4] = {};

  // staging: chunk j covers rows j*32 + wave*8 + (lane>>3); field lane&7
  const int colElem = (((lane&7) ^ ((lane>>3)&7)) << 3);
  const int srRow = wave*8 + (lane>>3);
  const ushort_t* pA[4]; const ushort_t* pB[4];
#pragma unroll
  for (int j=0;j<4;j++){
    long rA = min((long)(bm + j*32 + srRow), (long)M-1);
    long rB = min((long)(bn + j*32 + srRow), (long)N-1);
    pA[j] = A + rA*lda + colElem;
    pB[j] = Bt + rB*ldb + colElem;
  }

  const int lr = lane&15, g = lane>>4;
  const int e7 = lr & 7;

  for (int kt = 0; kt < K; kt += 64) {
    __syncthreads();                       // protect LDS from prior step's reads
#pragma unroll
    for (int j=0;j<4;j++) GLDS16(pA[j] + kt, As + j*4096 + wave*1024);
#pragma unroll
    for (int j=0;j<4;j++) GLDS16(pB[j] + kt, Bs + j*4096 + wave*1024);
    __syncthreads();                       // publish (drains vmcnt)
#pragma unroll
    for (int s=0; s<2; ++s){
      const int fld = (((g + 4*s) ^ e7) << 4);
      short8 af[4], bfv[4];
#pragma unroll
      for (int m=0;m<4;m++) af[m]  = *(const short8*)(As + (wr*64+m*16+lr)*128 + fld);
#pragma unroll
      for (int n=0;n<4;n++) bfv[n] = *(const short8*)(Bs + (wc*64+n*16+lr)*128 + fld);
#pragma unroll
      for (int m=0;m<4;m++)
#pragma unroll
        for (int n=0;n<4;n++)
          acc[m][n] = __builtin_amdgcn_mfma_f32_16x16x32_bf16(af[m], bfv[n], acc[m][n], 0, 0, 0);
    }
  }

  const int orow = bm + wr*64, ocol = bn + wc*64;
  const int rsub = g*4;
  float bv[4];
#pragma unroll
  for (int n=0;n<4;n++){
    const int col = ocol + n*16 + lr;
    bv[n] = (bias && col < N) ? bias[col] : 0.f;
  }
#pragma unroll
  for (int m=0;m<4;m++){
#pragma unroll
    for (int i=0;i<4;i++){
      const int row = orow + m*16 + rsub + i;
      if (row >= M) continue;
#pragma unroll
      for (int n=0;n<4;n++){
        const int col = ocol + n*16 + lr;
        if (col >= N) continue;
        float v = acc[m][n][i]*scale + bv[n];
        if (GELU) v = gelu_f(v);
        if (RES==1) v += RpF[(long)(row & resMask)*ldres + col];
        if (RES==2) v += b2f(RpB[(long)(row & resMask)*ldres + col]);
        if (Cf) Cf[(long)row*ldcf + col] = v;
        if (Cb) Cb[(long)row*ldcb + col] = f2b(v);
      }
    }
  }
}

// ---------------------------------------------------------------------------
// gemm_bt (double-buffer; small/batched).
// ---------------------------------------------------------------------------
template<bool GELU, int RES>
__global__ __launch_bounds__(256)
void gemm_bt(const ushort_t* __restrict__ A, const ushort_t* __restrict__ Bt,
             const float* __restrict__ bias, const void* __restrict__ Res,
             float* __restrict__ Cf, ushort_t* __restrict__ Cb,
             int M, int N, int K, int lda, int ldb, int ldres, int ldcf, int ldcb,
             int nb0,
             long sA0, long sA1, long sB0, long sB1, long sR0, long sR1,
             long sCf0, long sCf1, long sCb0, long sCb1, float scale, int resMask)
{
  const int z = blockIdx.z;
  const int b0 = z % nb0, b1 = z / nb0;
  A  += b0*sA0 + b1*sA1;
  Bt += b0*sB0 + b1*sB1;
  const float* RpF = 0; const ushort_t* RpB = 0;
  if (RES==1) RpF = (const float*)Res + b0*sR0 + b1*sR1;
  if (RES==2) RpB = (const ushort_t*)Res + b0*sR0 + b1*sR1;
  if (Cf) Cf += b0*sCf0 + b1*sCf1;
  if (Cb) Cb += b0*sCb0 + b1*sCb1;

  int by, bx; block_map(8, by, bx);
  const int bm = by*128, bn = bx*128;

  __shared__ __align__(16) ushort_t As[2][4096];
  __shared__ __align__(16) ushort_t Bs[2][4096];
  const int tid = threadIdx.x, lane = tid&63, wave = tid>>6;
  const int wr = wave>>1, wc = wave&1;

  f32x4 acc[4][4] = {};

  const int c0 = wave*64 + lane;
  const int c1 = c0 + 256;
  const long rA0 = min(bm + (c0>>2), M-1);
  const long rA1 = min(bm + (c1>>2), M-1);
  const long rB0 = min(bn + (c0>>2), N-1);
  const long rB1 = min(bn + (c1>>2), N-1);
  const ushort_t* pA0 = A + rA0*lda + (c0&3)*8;
  const ushort_t* pA1 = A + rA1*lda + (c1&3)*8;
  const ushort_t* pB0 = Bt + rB0*ldb + (c0&3)*8;
  const ushort_t* pB1 = Bt + rB1*ldb + (c1&3)*8;
  const int ldsOff = wave*512;

  const int lr = lane&15, lk = (lane>>4)*8;

#define STAGE(buf, kt) do { \
    GLDS16(pA0 + (kt), &As[buf][ldsOff]); \
    GLDS16(pA1 + (kt), &As[buf][2048 + ldsOff]); \
    GLDS16(pB0 + (kt), &Bs[buf][ldsOff]); \
    GLDS16(pB1 + (kt), &Bs[buf][2048 + ldsOff]); \
  } while(0)

  STAGE(0, 0);
  __syncthreads();
  int cur = 0;
  for (int kt = 0; kt < K; kt += 32) {
    if (kt + 32 < K) STAGE(cur^1, kt+32);
    short8 af[4], bfv[4];
#pragma unroll
    for (int m=0;m<4;m++) af[m]  = *(const short8*)(&As[cur][(wr*64+m*16+lr)*32 + lk]);
#pragma unroll
    for (int n=0;n<4;n++) bfv[n] = *(const short8*)(&Bs[cur][(wc*64+n*16+lr)*32 + lk]);
#pragma unroll
    for (int m=0;m<4;m++)
#pragma unroll
      for (int n=0;n<4;n++)
        acc[m][n] = __builtin_amdgcn_mfma_f32_16x16x32_bf16(af[m], bfv[n], acc[m][n], 0, 0, 0);
    __syncthreads();
    cur ^= 1;
  }
#undef STAGE

  const int orow = bm + wr*64, ocol = bn + wc*64;
  const int rsub = (lane>>4)*4;
  float bv[4];
#pragma unroll
  for (int n=0;n<4;n++){
    const int col = ocol + n*16 + lr;
    bv[n] = (bias && col < N) ? bias[col] : 0.f;
  }
#pragma unroll
  for (int m=0;m<4;m++){
#pragma unroll
    for (int i=0;i<4;i++){
      const int row = orow + m*16 + rsub + i;
      if (row >= M) continue;
#pragma unroll
      for (int n=0;n<4;n++){
        const int col = ocol + n*16 + lr;
        if (col >= N) continue;
        float v = acc[m][n][i]*scale + bv[n];
        if (GELU) v = gelu_f(v);
        if (RES==1) v += RpF[(long)(row & resMask)*ldres + col];
        if (RES==2) v += b2f(RpB[(long)(row & resMask)*ldres + col]);
        if (Cf) Cf[(long)row*ldcf + col] = v;
        if (Cb) Cb[(long)row*ldcb + col] = f2b(v);
      }
    }
  }
}

// ---------------------------------------------------------------------------
// Fused two-pass flash attention (refcheck-proven).
// ---------------------------------------------------------------------------
template<bool WRITEP>
__global__ __launch_bounds__(256)
void fattn_k(const ushort_t* __restrict__ Qb, const ushort_t* __restrict__ KVb,
             const ushort_t* __restrict__ Vtb, ushort_t* __restrict__ Ob,
             ushort_t* __restrict__ Pb,
             int LK, int ldkv, int qRowsPerB, int oRowsPerB, float scale)
{
  const int z = blockIdx.z, b = z >> 4, h = z & 15;
  const int qt = blockIdx.x;
  const int tid = threadIdx.x, lane = tid & 63, wave = tid >> 6;
  const int lr = lane & 15, g = lane >> 4;

  __shared__ __align__(16) ushort_t Kls[64*68];
  __shared__ __align__(16) ushort_t Vtls[64*68];
  __shared__ __align__(16) ushort_t Pls[64*68];

  const long qrow = (long)b*qRowsPerB + qt*64 + wave*16 + lr;
  const short8 aq0 = *(const short8*)(Qb + qrow*1024 + h*64 + g*8);
  const short8 aq1 = *(const short8*)(Qb + qrow*1024 + h*64 + 32 + g*8);

  const ushort_t* Kbase = KVb + (long)b*LK*ldkv + h*64;
  const ushort_t* Vtbase = Vtb + (long)(b*16+h)*64*LK;

  const int ntiles = LK >> 6;
  const int r0 = tid>>3, d0c = (tid&7)*8;
  const int r1 = r0 + 32;

  float m[4] = {-3e30f,-3e30f,-3e30f,-3e30f};
  float l[4] = {0.f,0.f,0.f,0.f};

  for (int t=0; t<ntiles; ++t){
    __syncthreads();
    { short8 v0 = *(const short8*)(Kbase + (long)(t*64 + r0)*ldkv + d0c);
      short8 v1 = *(const short8*)(Kbase + (long)(t*64 + r1)*ldkv + d0c);
      *(short8*)(Kls + r0*68 + d0c) = v0;
      *(short8*)(Kls + r1*68 + d0c) = v1; }
    __syncthreads();
    f32x4 s[4];
#pragma unroll
    for(int n=0;n<4;n++){
      s[n] = (f32x4){0.f,0.f,0.f,0.f};
      short8 bk0 = *(const short8*)(Kls + (n*16+lr)*68 + g*8);
      short8 bk1 = *(const short8*)(Kls + (n*16+lr)*68 + 32 + g*8);
      s[n] = __builtin_amdgcn_mfma_f32_16x16x32_bf16(aq0, bk0, s[n],0,0,0);
      s[n] = __builtin_amdgcn_mfma_f32_16x16x32_bf16(aq1, bk1, s[n],0,0,0);
    }
#pragma unroll
    for(int i=0;i<4;i++){
      float mx = fmaxf(fmaxf(s[0][i],s[1][i]), fmaxf(s[2][i],s[3][i])) * scale;
#pragma unroll
      for(int o2=1;o2<16;o2<<=1) mx = fmaxf(mx, __shfl_xor(mx,o2));
      float mnew = fmaxf(m[i], mx);
      float sum = __expf(s[0][i]*scale-mnew)+__expf(s[1][i]*scale-mnew)
                + __expf(s[2][i]*scale-mnew)+__expf(s[3][i]*scale-mnew);
#pragma unroll
      for(int o2=1;o2<16;o2<<=1) sum += __shfl_xor(sum,o2);
      l[i] = l[i]*__expf(m[i]-mnew) + sum;
      m[i] = mnew;
    }
  }
  float invl[4];
#pragma unroll
  for(int i=0;i<4;i++) invl[i] = 1.f/l[i];

  f32x4 o[4];
#pragma unroll
  for(int n=0;n<4;n++) o[n] = (f32x4){0.f,0.f,0.f,0.f};

  long pbase = 0;
  if (WRITEP) pbase = ((long)(b*16+h)*1024 + qt*64 + wave*16)*320 + lr;

  for (int t=0; t<ntiles; ++t){
    __syncthreads();
    { short8 v0 = *(const short8*)(Kbase + (long)(t*64 + r0)*ldkv + d0c);
      short8 v1 = *(const short8*)(Kbase + (long)(t*64 + r1)*ldkv + d0c);
      short8 w0 = *(const short8*)(Vtbase + (long)r0*LK + t*64 + d0c);
      short8 w1 = *(const short8*)(Vtbase + (long)r1*LK + t*64 + d0c);
      *(short8*)(Kls + r0*68 + d0c) = v0;
      *(short8*)(Kls + r1*68 + d0c) = v1;
      *(short8*)(Vtls + r0*68 + d0c) = w0;
      *(short8*)(Vtls + r1*68 + d0c) = w1; }
    __syncthreads();
    f32x4 s[4];
#pragma unroll
    for(int n=0;n<4;n++){
      s[n] = (f32x4){0.f,0.f,0.f,0.f};
      short8 bk0 = *(const short8*)(Kls + (n*16+lr)*68 + g*8);
      short8 bk1 = *(const short8*)(Kls + (n*16+lr)*68 + 32 + g*8);
      s[n] = __builtin_amdgcn_mfma_f32_16x16x32_bf16(aq0, bk0, s[n],0,0,0);
      s[n] = __builtin_amdgcn_mfma_f32_16x16x32_bf16(aq1, bk1, s[n],0,0,0);
    }
#pragma unroll
    for(int n=0;n<4;n++){
#pragma unroll
      for(int i=0;i<4;i++){
        float e = __expf(s[n][i]*scale - m[i]);
        Pls[(wave*16 + g*4 + i)*68 + n*16 + lr] = f2b(e);
        if (WRITEP) Pb[pbase + (long)(g*4+i)*320 + t*64 + n*16] = f2b(e*invl[i]);
      }
    }
    short8 pa0 = *(const short8*)(Pls + (wave*16+lr)*68 + g*8);
    short8 pa1 = *(const short8*)(Pls + (wave*16+lr)*68 + 32 + g*8);
#pragma unroll
    for(int nd=0; nd<4; nd++){
      short8 vb0 = *(const short8*)(Vtls + (nd*16+lr)*68 + g*8);
      short8 vb1 = *(const short8*)(Vtls + (nd*16+lr)*68 + 32 + g*8);
      o[nd] = __builtin_amdgcn_mfma_f32_16x16x32_bf16(pa0, vb0, o[nd],0,0,0);
      o[nd] = __builtin_amdgcn_mfma_f32_16x16x32_bf16(pa1, vb1, o[nd],0,0,0);
    }
  }
  const long orow0 = (long)b*oRowsPerB + qt*64 + wave*16 + g*4;
#pragma unroll
  for(int nd=0;nd<4;nd++)
#pragma unroll
    for(int i=0;i<4;i++)
      Ob[(orow0+i)*1024 + h*64 + nd*16 + lr] = f2b(o[nd][i]*invl[i]);
}

__global__ __launch_bounds__(256)
void tcvt_k(const float* __restrict__ src, ushort_t* __restrict__ dst, int R, int C)
{
  __shared__ float t[32][33];
  int c0 = blockIdx.x*32, r0 = blockIdx.y*32;
  int tx = threadIdx.x & 31, ty = threadIdx.x >> 5;
  for (int i=ty;i<32;i+=8){ int r=r0+i, c=c0+tx; t[i][tx] = (r<R && c<C) ? src[(long)r*C + c] : 0.f; }
  __syncthreads();
  for (int i=ty;i<32;i+=8){ int c=c0+i, r=r0+tx; if (c<C && r<R) dst[(long)c*R + r] = f2b(t[tx][i]); }
}

__global__ __launch_bounds__(256)
void cvt_rows_k(const float* __restrict__ src, ushort_t* __restrict__ dst,
                long total, int R, long dstBS, long dstRO)
{
  long e = ((long)blockIdx.x*256 + threadIdx.x)*4;
  if (e >= total) return;
  long rc = e >> 10; int c = (int)(e & 1023);
  int r = (int)(rc % R); long b = rc / R;
  float4 v = *(const float4*)(src + e);
  ushort4 o; o.x=f2b(v.x); o.y=f2b(v.y); o.z=f2b(v.z); o.w=f2b(v.w);
  *(ushort4*)(dst + (b*dstBS + dstRO + r)*1024 + c) = o;
}

// ctx (8x256x1024 fp32) -> kv rows [0,256) (BS 1280) AND kv2 rows [0,256) (BS 320)
__global__ __launch_bounds__(256)
void cvt_ctx2_k(const float* __restrict__ src, ushort_t* __restrict__ d1, ushort_t* __restrict__ d2)
{
  long e = ((long)blockIdx.x*256 + threadIdx.x)*4;   // grid covers 8*256*1024
  long rc = e >> 10; int c = (int)(e & 1023);
  int r = (int)(rc & 255); long b = rc >> 8;
  float4 v = *(const float4*)(src + e);
  ushort4 o; o.x=f2b(v.x); o.y=f2b(v.y); o.z=f2b(v.z); o.w=f2b(v.w);
  *(ushort4*)(d1 + (b*1280 + r)*1024 + c) = o;
  *(ushort4*)(d2 + (b*320  + r)*1024 + c) = o;
}

__global__ __launch_bounds__(256)
void vtrans_k(const ushort_t* __restrict__ V, ushort_t* __restrict__ Vt,
              int Lk, int ldv, int coloff)
{
  int b = blockIdx.z, h = blockIdx.y, k0 = blockIdx.x*32;
  __shared__ ushort_t t[32][65];
  int tx = threadIdx.x & 63, ty = threadIdx.x >> 6;
  for (int i=ty;i<32;i+=4) t[i][tx] = V[((long)b*Lk + k0 + i)*ldv + coloff + h*64 + tx];
  __syncthreads();
  int kk = threadIdx.x & 31, n0 = threadIdx.x >> 5;
  for (int n=n0;n<64;n+=8) Vt[((long)(b*16+h)*64 + n)*Lk + k0 + kk] = t[kk][n];
}

__global__ __launch_bounds__(256)
void ln2x_k(const float* __restrict__ x,
            const float* __restrict__ g1, const float* __restrict__ b1,
            const float* __restrict__ g2, const float* __restrict__ b2,
            float* __restrict__ y1f, ushort_t* __restrict__ y1b, ushort_t* __restrict__ y2b)
{
  const long row = blockIdx.x;
  int tid = threadIdx.x, lane = tid&63, wave = tid>>6;
  __shared__ float red[8], red2[8];
  float4 v = ((const float4*)(x + row*1024))[tid];
  float s = v.x+v.y+v.z+v.w;
  for (int o=32;o;o>>=1) s += __shfl_down(s,o);
  if (lane==0) red[wave]=s;
  __syncthreads();
  float mean = (red[0]+red[1]+red[2]+red[3])*(1.f/1024.f);
  float d0=v.x-mean, d1=v.y-mean, d2=v.z-mean, d3=v.w-mean;
  float q = d0*d0+d1*d1+d2*d2+d3*d3;
  for (int o=32;o;o>>=1) q += __shfl_down(q,o);
  if (lane==0) red[4+wave]=q;
  __syncthreads();
  float var = (red[4]+red[5]+red[6]+red[7])*(1.f/1024.f);
  float rs = rsqrtf(var+1e-5f);
  float4 gg=((const float4*)g1)[tid], bb=((const float4*)b1)[tid];
  float y0=d0*rs*gg.x+bb.x, y1v=d1*rs*gg.y+bb.y, y2v=d2*rs*gg.z+bb.z, y3=d3*rs*gg.w+bb.w;
  if (y1f) ((float4*)(y1f+row*1024))[tid] = make_float4(y0,y1v,y2v,y3);
  if (y1b){ ushort4 o4; o4.x=f2b(y0); o4.y=f2b(y1v); o4.z=f2b(y2v); o4.w=f2b(y3);
            ((ushort4*)(y1b+row*1024))[tid]=o4; }
  float s2 = y0+y1v+y2v+y3;
  for (int o=32;o;o>>=1) s2 += __shfl_down(s2,o);
  if (lane==0) red2[wave]=s2;
  __syncthreads();
  float mean2 = (red2[0]+red2[1]+red2[2]+red2[3])*(1.f/1024.f);
  float e0=y0-mean2,e1=y1v-mean2,e2=y2v-mean2,e3=y3-mean2;
  float q2 = e0*e0+e1*e1+e2*e2+e3*e3;
  for (int o=32;o;o>>=1) q2 += __shfl_down(q2,o);
  if (lane==0) red2[4+wave]=q2;
  __syncthreads();
  float var2 = (red2[4]+red2[5]+red2[6]+red2[7])*(1.f/1024.f);
  float rs2 = rsqrtf(var2+1e-5f);
  float4 g2v=((const float4*)g2)[tid], b2v=((const float4*)b2)[tid];
  ushort4 o4;
  o4.x=f2b(e0*rs2*g2v.x+b2v.x); o4.y=f2b(e1*rs2*g2v.y+b2v.y);
  o4.z=f2b(e2*rs2*g2v.z+b2v.z); o4.w=f2b(e3*rs2*g2v.w+b2v.w);
  ((ushort4*)(y2b+row*1024))[tid]=o4;
}

__global__ __launch_bounds__(256)
void w2ent_k(const ushort_t* __restrict__ P, float* __restrict__ rowent)
{
  int wid = (int)((blockIdx.x*256 + threadIdx.x) >> 6);
  int lane = threadIdx.x & 63;
  int b = wid >> 10, q = wid & 1023;
  const ushort_t* base = P + ((long)(b*16)*1024 + q)*320;
  float acc = 0.f;
#pragma unroll
  for (int j=0;j<5;j++){
    int k = j*64 + lane;
    float s = 0.f;
#pragma unroll
    for (int h=0;h<16;h++) s += b2f(base[(long)h*327680 + k]);
    float p = fmaxf(s*(1.f/16.f), 1e-8f);
    acc += p*__logf(p);
  }
  for (int o=32;o;o>>=1) acc += __shfl_down(acc, o);
  if (lane==0) rowent[wid] = acc;
}

__global__ __launch_bounds__(256)
void entfin_k(const float* __restrict__ rowent, float* __restrict__ out)
{
  float s = 0.f;
  for (int i=threadIdx.x;i<8192;i+=256) s += rowent[i];
  __shared__ float red[4];
  for (int o=32;o;o>>=1) s += __shfl_down(s,o);
  if ((threadIdx.x&63)==0) red[threadIdx.x>>6]=s;
  __syncthreads();
  if (threadIdx.x==0) out[0] = -(red[0]+red[1]+red[2]+red[3]) * (1.f/8192.f);
}

__global__ void dbg_k(float* out, float a){ out[0] = -12345.f; out[1] = a; }

// ---------------------------------------------------------------------------
// variant: 0 = gemm_bt (db), 1 = gemm_sb (BK=64), 2 = gemm256
static void gemm(hipStream_t s, int variant, int mode,
                 const void* A, const void* Bt, const float* bias, const void* Res,
                 void* Cf, void* Cb,
                 int M, int N, int K, int lda, int ldb, int ldres, int ldcf, int ldcb,
                 int nz, int nb0,
                 long sA0, long sA1, long sB0, long sB1, long sR0, long sR1,
                 long sCf0, long sCf1, long sCb0, long sCb1, float scale, int resMask)
{
#define ARGS (const ushort_t*)A,(const ushort_t*)Bt,bias,Res,(float*)Cf,(ushort_t*)Cb,M,N,K,lda,ldb,ldres,ldcf,ldcb,nb0,sA0,sA1,sB0,sB1,sR0,sR1,sCf0,sCf1,sCb0,sCb1,scale,resMask
#define ARGS6 (const ushort_t*)A,(const ushort_t*)Bt,bias,Res,(float*)Cf,(ushort_t*)Cb,M,N,K,lda,ldb,ldres,ldcf,ldcb,nb0,sA0,sA1,sB0,sB1,sR0,sR1,sCf0,sCf1,sCb0,sCb1,scale
  if (variant == 2){
    dim3 g((N+127)/128, (M+255)/256, nz), b(512,1,1);
    if      (mode == 1) gemm256<true ,0><<<g,b,0,s>>>(ARGS6);
    else if (mode == 2) gemm256<false,1><<<g,b,0,s>>>(ARGS6);
    else if (mode == 3) gemm256<false,2><<<g,b,0,s>>>(ARGS6);
    else                gemm256<false,0><<<g,b,0,s>>>(ARGS6);
  } else if (variant == 1){
    dim3 g((N+127)/128, (M+127)/128, nz), b(256,1,1);
    if      (mode == 1) gemm_sb<true ,0><<<g,b,0,s>>>(ARGS);
    else if (mode == 2) gemm_sb<false,1><<<g,b,0,s>>>(ARGS);
    else if (mode == 3) gemm_sb<false,2><<<g,b,0,s>>>(ARGS);
    else                gemm_sb<false,0><<<g,b,0,s>>>(ARGS);
  } else {
    dim3 g((N+127)/128, (M+127)/128, nz), b(256,1,1);
    if      (mode == 1) gemm_bt<true ,0><<<g,b,0,s>>>(ARGS);
    else if (mode == 2) gemm_bt<false,1><<<g,b,0,s>>>(ARGS);
    else if (mode == 3) gemm_bt<false,2><<<g,b,0,s>>>(ARGS);
    else                gemm_bt<false,0><<<g,b,0,s>>>(ARGS);
  }
#undef ARGS
#undef ARGS6
}

extern "C" void kernel_launch(void* const* d_in, const int* in_sizes, int n_in,
                              void* d_out, int out_size, void* d_ws, size_t ws_size,
                              hipStream_t stream)
{
  const float* ptsIn = (const float*)d_in[0];
  const float* ctx   = (const float*)d_in[1];
  const float* induc = (const float*)d_in[2];
  const float* tiW[4]={(const float*)d_in[3],(const float*)d_in[4],(const float*)d_in[5],(const float*)d_in[6]};
  const float* tib[4]={(const float*)d_in[7],(const float*)d_in[8],(const float*)d_in[9],(const float*)d_in[10]};
  const float* tpW[4]={(const float*)d_in[11],(const float*)d_in[12],(const float*)d_in[13],(const float*)d_in[14]};
  const float* tpb[4]={(const float*)d_in[15],(const float*)d_in[16],(const float*)d_in[17],(const float*)d_in[18]};
  const float* iff_g=(const float*)d_in[19]; const float* iff_b=(const float*)d_in[20];
  const float* iffW1=(const float*)d_in[21]; const float* iff_b1=(const float*)d_in[22];
  const float* iffW2=(const float*)d_in[23]; const float* iff_b2=(const float*)d_in[24];
  const float* pff_g=(const float*)d_in[25]; const float* pff_b=(const float*)d_in[26];
  const float* pffW1=(const float*)d_in[27]; const float* pff_b1=(const float*)d_in[28];
  const float* pffW2=(const float*)d_in[29]; const float* pff_b2=(const float*)d_in[30];
  const float* ni_g=(const float*)d_in[31]; const float* ni_b=(const float*)d_in[32];
  const float* np_g=(const float*)d_in[33]; const float* np_b=(const float*)d_in[34];
  float* outF = (float*)d_out;

  char* ws = (char*)d_ws;
  size_t off = 0;
  auto alloc = [&](size_t bytes){ off=(off+255)&~(size_t)255; size_t o=off; off+=bytes; return o; };
  auto sub = [&](size_t& pp, size_t bytes){ pp=(pp+255)&~(size_t)255; size_t o=pp; pp+=bytes; return o; };

  // ---- persistent ----
  size_t o_tiQw  = alloc(1024L*1024*2);
  size_t o_tiKVw = alloc(2048L*1024*2);
  size_t o_tiOw  = alloc(1024L*1024*2);
  size_t o_tpQw  = alloc(1024L*1024*2);
  size_t o_tpKVw = alloc(2048L*1024*2);
  size_t o_tpOw  = alloc(1024L*1024*2);
  size_t o_iffW1t = alloc(4096L*1024*2);
  size_t o_iffW2t = alloc(4096L*1024*2);
  size_t o_pffW1t = alloc(4096L*1024*2);
  size_t o_pffW2t = alloc(4096L*1024*2);
  size_t o_bti  = alloc(2048*4);
  size_t o_btp  = alloc(2048*4);
  size_t o_indb = alloc(64L*1024*2);
  size_t o_kv   = alloc(10240L*1024*2);
  size_t o_kv2  = alloc(2560L*1024*2);
  size_t o_rowent = alloc(8192*4);
  off=(off+255)&~(size_t)255;
  size_t arena = off;

  // ---- ti phase ----
  size_t p = arena;
  size_t o_Qti     = sub(p, 64L*1024*2);
  size_t o_KVti    = sub(p, 10240L*2048*2);
  size_t o_Vtti    = sub(p, 8192L*1280*2);
  size_t o_attnOti = sub(p, 512L*1024*2);
  size_t o_t1      = sub(p, 512L*1024*4);
  size_t o_ind1    = sub(p, 512L*1024*4);
  size_t o_h0i     = sub(p, 512L*1024*2);
  size_t o_h1i     = sub(p, 512L*4096*2);
  size_t need1 = p;
  // ---- tp phase ----
  p = arena;
  size_t o_attnOtp = sub(p, 8192L*1024*2);
  size_t shared = p;
  size_t o_Qtp  = sub(p, 8192L*1024*2);
  size_t o_KVtp = sub(p, 2560L*2048*2);
  size_t o_Vttp = sub(p, 8192L*320*2);
  size_t o_P    = sub(p, 8L*16*1024*320*2);
  size_t need3 = p;
  p = shared;
  size_t o_t2   = sub(p, 8192L*1024*4);
  size_t o_pts1 = sub(p, 8192L*1024*2);
  size_t o_h0p  = sub(p, 8192L*1024*2);
  size_t o_h1p  = sub(p, 8192L*4096*2);
  size_t need4 = p;

  size_t need = need1;
  if (need3>need) need=need3;
  if (need4>need) need=need4;
  if (need > ws_size){ dbg_k<<<1,1,0,stream>>>(outF, (float)(need>>20)); return; }

#define WP(o) ((void*)(ws + (o)))
#define BP(o) ((ushort_t*)(ws + (o)))
#define FP(o) ((float*)(ws + (o)))

  // ---- weights -> bf16 transposed ----
  tcvt_k<<<dim3(32,32),256,0,stream>>>(tiW[0], BP(o_tiQw), 1024, 1024);
  tcvt_k<<<dim3(32,32),256,0,stream>>>(tiW[1], BP(o_tiKVw), 1024, 1024);
  tcvt_k<<<dim3(32,32),256,0,stream>>>(tiW[2], BP(o_tiKVw) + 1024L*1024, 1024, 1024);
  tcvt_k<<<dim3(32,32),256,0,stream>>>(tiW[3], BP(o_tiOw), 1024, 1024);
  tcvt_k<<<dim3(32,32),256,0,stream>>>(tpW[0], BP(o_tpQw), 1024, 1024);
  tcvt_k<<<dim3(32,32),256,0,stream>>>(tpW[1], BP(o_tpKVw), 1024, 1024);
  tcvt_k<<<dim3(32,32),256,0,stream>>>(tpW[2], BP(o_tpKVw) + 1024L*1024, 1024, 1024);
  tcvt_k<<<dim3(32,32),256,0,stream>>>(tpW[3], BP(o_tpOw), 1024, 1024);
  tcvt_k<<<dim3(128,32),256,0,stream>>>(iffW1, BP(o_iffW1t), 1024, 4096);
  tcvt_k<<<dim3(32,128),256,0,stream>>>(iffW2, BP(o_iffW2t), 4096, 1024);
  tcvt_k<<<dim3(128,32),256,0,stream>>>(pffW1, BP(o_pffW1t), 1024, 4096);
  tcvt_k<<<dim3(32,128),256,0,stream>>>(pffW2, BP(o_pffW2t), 4096, 1024);
  hipMemcpyAsync(WP(o_bti), (const void*)tib[1], 1024*4, hipMemcpyDeviceToDevice, stream);
  hipMemcpyAsync((void*)(ws+o_bti+1024*4), (const void*)tib[2], 1024*4, hipMemcpyDeviceToDevice, stream);
  hipMemcpyAsync(WP(o_btp), (const void*)tpb[1], 1024*4, hipMemcpyDeviceToDevice, stream);
  hipMemcpyAsync((void*)(ws+o_btp+1024*4), (const void*)tpb[2], 1024*4, hipMemcpyDeviceToDevice, stream);

  // ---- activations -> bf16 (ctx read once, written to kv AND kv2) ----
  cvt_ctx2_k<<<2048,256,0,stream>>>(ctx, BP(o_kv), BP(o_kv2));
  cvt_rows_k<<<8192,256,0,stream>>>(ptsIn, BP(o_kv),  8L*1024*1024, 1024, 1280, 256);
  cvt_rows_k<<<64,256,0,stream>>>(induc,   BP(o_indb), 64L*1024, 64, 64, 0);

  // ---- to_induced ----
  gemm(stream,0,0, WP(o_indb), WP(o_tiQw), tib[0], 0, 0, WP(o_Qti),
       64,1024,1024, 1024,1024,0,0,1024, 1,1, 0,0,0,0,0,0,0,0,0,0, 1.f,-1);
  gemm(stream,1,0, WP(o_kv), WP(o_tiKVw), FP(o_bti), 0, 0, WP(o_KVti),
       10240,2048,1024, 1024,1024,0,0,2048, 1,1, 0,0,0,0,0,0,0,0,0,0, 1.f,-1);
  vtrans_k<<<dim3(40,16,8),256,0,stream>>>(BP(o_KVti), BP(o_Vtti), 1280, 2048, 1024);
  fattn_k<false><<<dim3(1,1,128),256,0,stream>>>(BP(o_Qti), BP(o_KVti), BP(o_Vtti),
       BP(o_attnOti), (ushort_t*)0, 1280, 2048, 0, 64, 0.125f);
  gemm(stream,0,2, WP(o_attnOti), WP(o_tiOw), tib[3], (const void*)induc, WP(o_t1), 0,
       512,1024,1024, 1024,1024,1024,1024,0, 1,1, 0,0,0,0,0,0,0,0,0,0, 1.f,63);
  ln2x_k<<<512,256,0,stream>>>(FP(o_t1), ni_g, ni_b, iff_g, iff_b, FP(o_ind1), 0, BP(o_h0i));
  gemm(stream,0,1, WP(o_h0i), WP(o_iffW1t), iff_b1, 0, 0, WP(o_h1i),
       512,4096,1024, 1024,1024,0,0,4096, 1,1, 0,0,0,0,0,0,0,0,0,0, 1.f,-1);
  gemm(stream,0,2, WP(o_h1i), WP(o_iffW2t), iff_b2, WP(o_ind1), 0, BP(o_kv2) + 262144,
       64,1024,4096, 4096,4096,1024,0,1024, 8,8,
       262144,0, 0,0, 65536,0, 0,0, 327680,0, 1.f,-1);

  // ---- to_points ----
  gemm(stream,2,0, BP(o_kv) + 262144, WP(o_tpQw), tpb[0], 0, 0, WP(o_Qtp),
       1024,1024,1024, 1024,1024,0,0,1024, 8,8,
       1310720,0, 0,0, 0,0, 0,0, 1048576,0, 1.f,-1);
  gemm(stream,0,0, WP(o_kv2), WP(o_tpKVw), FP(o_btp), 0, 0, WP(o_KVtp),
       2560,2048,1024, 1024,1024,0,0,2048, 1,1, 0,0,0,0,0,0,0,0,0,0, 1.f,-1);
  vtrans_k<<<dim3(10,16,8),256,0,stream>>>(BP(o_KVtp), BP(o_Vttp), 320, 2048, 1024);
  fattn_k<true><<<dim3(16,1,128),256,0,stream>>>(BP(o_Qtp), BP(o_KVtp), BP(o_Vttp),
       BP(o_attnOtp), BP(o_P), 320, 2048, 1024, 1024, 0.125f);
  w2ent_k<<<2048,256,0,stream>>>(BP(o_P), FP(o_rowent));
  entfin_k<<<1,256,0,stream>>>(FP(o_rowent), outF + (out_size-1));
  gemm(stream,2,2, WP(o_attnOtp), WP(o_tpOw), tpb[3], (const void*)ptsIn, WP(o_t2), 0,
       8192,1024,1024, 1024,1024,1024,1024,0, 1,1, 0,0,0,0,0,0,0,0,0,0, 1.f,-1);
  ln2x_k<<<8192,256,0,stream>>>(FP(o_t2), np_g, np_b, pff_g, pff_b, 0, BP(o_pts1), BP(o_h0p));
  gemm(stream,1,1, WP(o_h0p), WP(o_pffW1t), pff_b1, 0, 0, WP(o_h1p),
       8192,4096,1024, 1024,1024,0,0,4096, 1,1, 0,0,0,0,0,0,0,0,0,0, 1.f,-1);
  gemm(stream,2,3, WP(o_h1p), WP(o_pffW2t), pff_b2, WP(o_pts1), outF, 0,
       8192,1024,4096, 4096,4096,1024,1024,0, 1,1, 0,0,0,0,0,0,0,0,0,0, 1.f,-1);

#undef WP
#undef BP
#undef FP
}